// Round 4
// baseline (564.754 us; speedup 1.0000x reference)
//
#include <hip/hip_runtime.h>
#include <cmath>
#include <cstddef>

namespace {

constexpr int cB = 2, cL = 2048, cS = 2048, cD = 1024, cH = 16, cNS = 8, cNSLOT = 512, cHD = 64;

typedef __attribute__((ext_vector_type(8))) short short8;
typedef __attribute__((ext_vector_type(4))) float f32x4;

#define MFMA16(a, b, c) __builtin_amdgcn_mfma_f32_16x16x32_bf16((a), (b), (c), 0, 0, 0)

__device__ __forceinline__ float sigmoidf_(float x) { return 1.f / (1.f + __expf(-x)); }

__device__ __forceinline__ unsigned short f2bf(float x) {
  union { float f; unsigned u; } c; c.f = x;
  unsigned r = c.u + 0x7FFFu + ((c.u >> 16) & 1u);
  return (unsigned short)(r >> 16);
}
__device__ __forceinline__ float bf2f(unsigned short h) {
  union { unsigned u; float f; } c; c.u = ((unsigned)h) << 16;
  return c.f;
}

// truncation hi-split + RNE lo-split, packed (lo<<16 | hi) in one uint. 5 VALU.
__device__ __forceinline__ unsigned pack_split(float v) {
  union { float f; unsigned u; } c; c.f = v;
  const unsigned rh = c.u & 0xffff0000u;
  union { float f; unsigned u; } d; d.f = v - __uint_as_float(rh);
  const unsigned t = d.u + 0x7fffu + ((d.u >> 16) & 1u);
  // bytes: [c.b2, c.b3, t.b2, t.b3] -> low16 = hi-bf16, high16 = lo-bf16
  return __builtin_amdgcn_perm(t, c.u, 0x07060302u);
}

__device__ __forceinline__ void unpack8(const uint4 a, const uint4 b, short8& ph, short8& pl) {
  const unsigned p[8] = {a.x, a.y, a.z, a.w, b.x, b.y, b.z, b.w};
  union { unsigned u[4]; short8 s; } H, L;
#pragma unroll
  for (int i = 0; i < 4; i++) {
    H.u[i] = __builtin_amdgcn_perm(p[2 * i + 1], p[2 * i], 0x05040100u);
    L.u[i] = __builtin_amdgcn_perm(p[2 * i + 1], p[2 * i], 0x07060302u);
  }
  ph = H.s;
  pl = L.s;
}

// async global->LDS 16B per lane. lds ptr must be wave-uniform base; HW writes base + lane*16.
__device__ __forceinline__ void async16(const void* g, void* l) {
  __builtin_amdgcn_global_load_lds((const __attribute__((address_space(1))) void*)g,
                                   (__attribute__((address_space(3))) void*)l, 16, 0, 0);
}

// ---------------- weight split: 4 matrices of 1M floats -> hi/lo bf16 ----------------
__global__ __launch_bounds__(256) void wsplit_kernel(
    const float* __restrict__ Wq, const float* __restrict__ Wk,
    const float* __restrict__ Wv, const float* __restrict__ Wo,
    unsigned short* __restrict__ Wqh, unsigned short* __restrict__ Wql,
    unsigned short* __restrict__ Wkh, unsigned short* __restrict__ Wkl,
    unsigned short* __restrict__ Wvh, unsigned short* __restrict__ Wvl,
    unsigned short* __restrict__ Woh, unsigned short* __restrict__ Wol) {
  const int wid = blockIdx.x >> 9;  // 512 blocks per weight
  const size_t off = ((size_t)(blockIdx.x & 511) * 256 + threadIdx.x) * 8;
  const float* src = wid == 0 ? Wq : wid == 1 ? Wk : wid == 2 ? Wv : Wo;
  unsigned short* dh = wid == 0 ? Wqh : wid == 1 ? Wkh : wid == 2 ? Wvh : Woh;
  unsigned short* dl = wid == 0 ? Wql : wid == 1 ? Wkl : wid == 2 ? Wvl : Wol;
  const float4 a = *(const float4*)(src + off);
  const float4 b = *(const float4*)(src + off + 4);
  float v[8] = {a.x, a.y, a.z, a.w, b.x, b.y, b.z, b.w};
  unsigned short h8[8], l8[8];
#pragma unroll
  for (int j = 0; j < 8; j++) {
    h8[j] = f2bf(v[j]);
    l8[j] = f2bf(v[j] - bf2f(h8[j]));
  }
  *(uint4*)(dh + off) = *(uint4*)h8;
  *(uint4*)(dl + off) = *(uint4*)l8;
}

// ---------------- LayerNorm of E_slots rows -> hi/lo bf16 ----------------
__global__ __launch_bounds__(256) void ln_slots_kernel(const float* __restrict__ E,
                                                       const float* __restrict__ gamma,
                                                       const float* __restrict__ beta,
                                                       unsigned short* __restrict__ mh,
                                                       unsigned short* __restrict__ ml) {
  __shared__ float rbuf[8];
  const int row = blockIdx.x;
  const int tid = threadIdx.x;
  const int d0 = tid * 4;
  const float4 x = *(const float4*)(E + (size_t)row * cD + d0);
  float s1 = x.x + x.y + x.z + x.w;
  float s2 = x.x * x.x + x.y * x.y + x.z * x.z + x.w * x.w;
#pragma unroll
  for (int o = 32; o > 0; o >>= 1) { s1 += __shfl_xor(s1, o, 64); s2 += __shfl_xor(s2, o, 64); }
  if ((tid & 63) == 0) { rbuf[tid >> 6] = s1; rbuf[4 + (tid >> 6)] = s2; }
  __syncthreads();
  s1 = rbuf[0] + rbuf[1] + rbuf[2] + rbuf[3];
  s2 = rbuf[4] + rbuf[5] + rbuf[6] + rbuf[7];
  const float mean = s1 * (1.f / cD);
  const float var = s2 * (1.f / cD) - mean * mean;
  const float inv = rsqrtf(var + 1e-5f);
  const float4 g = *(const float4*)(gamma + d0);
  const float4 b = *(const float4*)(beta + d0);
  float y[4];
  y[0] = (x.x - mean) * inv * g.x + b.x;
  y[1] = (x.y - mean) * inv * g.y + b.y;
  y[2] = (x.z - mean) * inv * g.z + b.z;
  y[3] = (x.w - mean) * inv * g.w + b.w;
  unsigned short h4[4], l4[4];
#pragma unroll
  for (int j = 0; j < 4; j++) {
    h4[j] = f2bf(y[j]);
    l4[j] = f2bf(y[j] - bf2f(h4[j]));
  }
  *(uint2*)(mh + (size_t)row * cD + d0) = *(uint2*)h4;
  *(uint2*)(ml + (size_t)row * cD + d0) = *(uint2*)l4;
}

// ---------------- Q-side: Y = LN(x_q * SiLU(C_seq @ Wpe^T)) -> hi/lo bf16 ----------------
__global__ __launch_bounds__(256) void qgate_ln_kernel(const float* __restrict__ xq,
                                                       const float* __restrict__ Cseq,
                                                       const float* __restrict__ Wpe,
                                                       const float* __restrict__ gamma,
                                                       const float* __restrict__ beta,
                                                       unsigned short* __restrict__ Yh,
                                                       unsigned short* __restrict__ Yl) {
  __shared__ float sC[cNS];
  __shared__ float rbuf[8];
  const int row = blockIdx.x;
  const int tid = threadIdx.x;
  if (tid < cNS) sC[tid] = Cseq[(size_t)row * cNS + tid];
  __syncthreads();
  const int d0 = tid * 4;
  const float4 x = *(const float4*)(xq + (size_t)row * cD + d0);
  float y[4];
  float s1 = 0.f, s2 = 0.f;
#pragma unroll
  for (int j = 0; j < 4; j++) {
    const float* wr = Wpe + (size_t)(d0 + j) * cNS;
    float gs = 0.f;
#pragma unroll
    for (int m = 0; m < cNS; m++) gs += sC[m] * wr[m];
    const float val = ((const float*)&x)[j] * gs * sigmoidf_(gs);
    y[j] = val;
    s1 += val;
    s2 += val * val;
  }
#pragma unroll
  for (int o = 32; o > 0; o >>= 1) { s1 += __shfl_xor(s1, o, 64); s2 += __shfl_xor(s2, o, 64); }
  if ((tid & 63) == 0) { rbuf[tid >> 6] = s1; rbuf[4 + (tid >> 6)] = s2; }
  __syncthreads();
  s1 = rbuf[0] + rbuf[1] + rbuf[2] + rbuf[3];
  s2 = rbuf[4] + rbuf[5] + rbuf[6] + rbuf[7];
  const float mean = s1 * (1.f / cD);
  const float var = s2 * (1.f / cD) - mean * mean;
  const float inv = rsqrtf(var + 1e-5f);
  const float4 g = *(const float4*)(gamma + d0);
  const float4 b = *(const float4*)(beta + d0);
  float z[4];
  z[0] = (y[0] - mean) * inv * g.x + b.x;
  z[1] = (y[1] - mean) * inv * g.y + b.y;
  z[2] = (y[2] - mean) * inv * g.z + b.z;
  z[3] = (y[3] - mean) * inv * g.w + b.w;
  unsigned short h4[4], l4[4];
#pragma unroll
  for (int j = 0; j < 4; j++) {
    h4[j] = f2bf(z[j]);
    l4[j] = f2bf(z[j] - bf2f(h4[j]));
  }
  *(uint2*)(Yh + (size_t)row * cD + d0) = *(uint2*)h4;
  *(uint2*)(Yl + (size_t)row * cD + d0) = *(uint2*)l4;
}

// ---------------- gate_kv[s, d] = SiLU( sum_m rho_m^(S-1-s) * Wpe[d, m] ) ----------------
__global__ __launch_bounds__(256) void gatekv_kernel(const float* __restrict__ rhos,
                                                     const float* __restrict__ Wpe,
                                                     float* __restrict__ gkv) {
  __shared__ float sC[cNS];
  const int s = blockIdx.x;
  const int tid = threadIdx.x;
  if (tid < cNS) {
    const float age = (float)(cS - 1 - s);
    sC[tid] = __expf(age * __logf(rhos[tid]));
  }
  __syncthreads();
  const int d0 = tid * 4;
  float4 o4;
#pragma unroll
  for (int j = 0; j < 4; j++) {
    const float* wr = Wpe + (size_t)(d0 + j) * cNS;
    float gs = 0.f;
#pragma unroll
    for (int m = 0; m < cNS; m++) gs += sC[m] * wr[m];
    ((float*)&o4)[j] = gs * sigmoidf_(gs);
  }
  *(float4*)(gkv + (size_t)s * cD + d0) = o4;
}

// ---------------- split-bf16 MFMA GEMM: C[M,N] = A[M,K] @ W[N,K]^T ----------------
// 128x128 tile, BK=32, 512 thr (8 waves, 4x2), double-buffered LDS w/ async prefetch.
// blockIdx.z selects (W,C) pair -> fuses K/V projections into one dispatch.
// MODE 0: fp32 out. MODE 1: scale then hi/lo bf16 split out.
template <int MODE>
__global__ __launch_bounds__(512) void gemm_sp_kernel(
    const unsigned short* __restrict__ Ahi, const unsigned short* __restrict__ Alo,
    const unsigned short* __restrict__ Whi0, const unsigned short* __restrict__ Wlo0,
    const unsigned short* __restrict__ Whi1, const unsigned short* __restrict__ Wlo1,
    float* __restrict__ Cf0, float* __restrict__ Cf1,
    unsigned short* __restrict__ Chi, unsigned short* __restrict__ Clo,
    int M, int N, int K, float scale) {
  __shared__ __align__(16) unsigned short sAh[2][128 * 32];
  __shared__ __align__(16) unsigned short sAl[2][128 * 32];
  __shared__ __align__(16) unsigned short sBh[2][128 * 32];
  __shared__ __align__(16) unsigned short sBl[2][128 * 32];
  const unsigned short* Whi = blockIdx.z ? Whi1 : Whi0;
  const unsigned short* Wlo = blockIdx.z ? Wlo1 : Wlo0;
  float* Cf = blockIdx.z ? Cf1 : Cf0;
  const int tid = threadIdx.x;
  const int wave = tid >> 6, lane = tid & 63;
  const int quad = lane >> 4, l16 = lane & 15;
  const int m0 = blockIdx.y * 128, n0 = blockIdx.x * 128;
  const int wy = wave >> 1, wx = wave & 1;           // wave tile: 32(m) x 64(n)
  const int srow = lane >> 2;                        // row within 16-row staging inst
  const int sg = (lane & 3) ^ ((lane >> 3) & 3);     // permuted global granule

  f32x4 acc[2][4];
#pragma unroll
  for (int i = 0; i < 2; i++)
#pragma unroll
    for (int j = 0; j < 4; j++) acc[i][j] = (f32x4){0.f, 0.f, 0.f, 0.f};

  auto stage = [&](int buf, int k0) {
    const int row = wave * 16 + srow;
    const size_t ga = (size_t)(m0 + row) * K + k0 + sg * 8;
    const size_t gb = (size_t)(n0 + row) * K + k0 + sg * 8;
    async16(Ahi + ga, &sAh[buf][wave * 512]);
    async16(Alo + ga, &sAl[buf][wave * 512]);
    async16(Whi + gb, &sBh[buf][wave * 512]);
    async16(Wlo + gb, &sBl[buf][wave * 512]);
  };

  stage(0, 0);
  __syncthreads();
  const int aswz = (l16 >> 1) & 3;
  int buf = 0;
  for (int k0 = 0; k0 < K; k0 += 32, buf ^= 1) {
    if (k0 + 32 < K) stage(buf ^ 1, k0 + 32);  // drains at iter-end barrier
    short8 bh[4], bl4[4];
#pragma unroll
    for (int t = 0; t < 4; t++) {
      const int br = (wx * 64 + t * 16 + l16) * 32 + ((quad ^ aswz) * 8);
      bh[t] = *(const short8*)&sBh[buf][br];
      bl4[t] = *(const short8*)&sBl[buf][br];
    }
#pragma unroll
    for (int ti = 0; ti < 2; ti++) {
      const int ar = (wy * 32 + ti * 16 + l16) * 32 + ((quad ^ aswz) * 8);
      const short8 ah = *(const short8*)&sAh[buf][ar];
      const short8 al4 = *(const short8*)&sAl[buf][ar];
#pragma unroll
      for (int tj = 0; tj < 4; tj++) {
        acc[ti][tj] = MFMA16(ah, bh[tj], acc[ti][tj]);
        acc[ti][tj] = MFMA16(al4, bh[tj], acc[ti][tj]);
        acc[ti][tj] = MFMA16(ah, bl4[tj], acc[ti][tj]);
      }
    }
    __syncthreads();
  }

#pragma unroll
  for (int ti = 0; ti < 2; ti++)
#pragma unroll
    for (int tj = 0; tj < 4; tj++) {
      const int row = m0 + wy * 32 + ti * 16 + quad * 4;
      const int col = n0 + wx * 64 + tj * 16 + l16;
#pragma unroll
      for (int r = 0; r < 4; r++) {
        const size_t idx = (size_t)(row + r) * N + col;
        if constexpr (MODE == 0) {
          Cf[idx] = acc[ti][tj][r];
        } else {
          const float v = acc[ti][tj][r] * scale;
          const unsigned short hi = f2bf(v);
          Chi[idx] = hi;
          Clo[idx] = f2bf(v - bf2f(hi));
        }
      }
    }
}

// ---------------- prep: K = gather(Ek)*gate, split hi/lo bf16, [B][S][D] ----------------
__global__ __launch_bounds__(256) void prep_k_kernel(const float* __restrict__ Ek,
                                                     const float* __restrict__ gkv,
                                                     const int* __restrict__ xidx,
                                                     unsigned short* __restrict__ Khi,
                                                     unsigned short* __restrict__ Klo) {
  const int t = blockIdx.x * 256 + threadIdx.x;
  const int d0 = (t & 127) * 8;
  const int s = (t >> 7) & (cS - 1);
  const int b = t >> 18;
  const int slot = xidx[b * cS + s];
  const float4 e0 = *(const float4*)(Ek + (size_t)slot * cD + d0);
  const float4 e1 = *(const float4*)(Ek + (size_t)slot * cD + d0 + 4);
  const float4 g0 = *(const float4*)(gkv + (size_t)s * cD + d0);
  const float4 g1 = *(const float4*)(gkv + (size_t)s * cD + d0 + 4);
  float v[8] = {e0.x * g0.x, e0.y * g0.y, e0.z * g0.z, e0.w * g0.w,
                e1.x * g1.x, e1.y * g1.y, e1.z * g1.z, e1.w * g1.w};
  unsigned short h8[8], l8[8];
#pragma unroll
  for (int j = 0; j < 8; j++) {
    h8[j] = f2bf(v[j]);
    l8[j] = f2bf(v[j] - bf2f(h8[j]));
  }
  const size_t off = (size_t)(b * cS + s) * cD + d0;
  *(uint4*)(Khi + off) = *(uint4*)h8;
  *(uint4*)(Klo + off) = *(uint4*)l8;
}

// ---------------- prep: Vt[b][d][s] = gather(Ev)*gate, split hi/lo bf16 (transposed) ----------------
__global__ __launch_bounds__(256) void prep_vt_kernel(const float* __restrict__ Ev,
                                                      const float* __restrict__ gkv,
                                                      const int* __restrict__ xidx,
                                                      unsigned short* __restrict__ Vthi,
                                                      unsigned short* __restrict__ Vtlo) {
  __shared__ float tile[64][65];
  const int s0 = blockIdx.x * 64, d0 = blockIdx.y * 64, b = blockIdx.z;
  const int tid = threadIdx.x;
  const int sl = tid >> 4;
  const int dl = (tid & 15) * 4;
#pragma unroll
  for (int it = 0; it < 4; it++) {
    const int s = s0 + sl + it * 16;
    const int slot = xidx[b * cS + s];
    const float4 e = *(const float4*)(Ev + (size_t)slot * cD + d0 + dl);
    const float4 g = *(const float4*)(gkv + (size_t)s * cD + d0 + dl);
    tile[sl + it * 16][dl + 0] = e.x * g.x;
    tile[sl + it * 16][dl + 1] = e.y * g.y;
    tile[sl + it * 16][dl + 2] = e.z * g.z;
    tile[sl + it * 16][dl + 3] = e.w * g.w;
  }
  __syncthreads();
  const int dr = tid >> 3;
  const int sc = (tid & 7) * 8;
#pragma unroll
  for (int it = 0; it < 2; it++) {
    const int d = d0 + dr + it * 32;
    unsigned short h8[8], l8[8];
#pragma unroll
    for (int j = 0; j < 8; j++) {
      const float v = tile[sc + j][dr + it * 32];
      h8[j] = f2bf(v);
      l8[j] = f2bf(v - bf2f(h8[j]));
    }
    const size_t off = (size_t)(b * cD + d) * cS + s0 + sc;
    *(uint4*)(Vthi + off) = *(uint4*)h8;
    *(uint4*)(Vtlo + off) = *(uint4*)l8;
  }
}

// ---------------- MFMA flash attention v3 ----------------
// grid (L/64, H, B) = 1024 blocks, 256 thr = 4 waves, wave owns 16 l-rows. s-chunk 64.
// Register double-buffer for K/V staging; softmax in exp2 domain (log2e folded into Q);
// denominator via ones-MFMA; P hi/lo packed into uint32 LDS.
__global__ __launch_bounds__(256, 3) void attn_mfma_kernel(
    const unsigned short* __restrict__ qhi, const unsigned short* __restrict__ qlo,
    const unsigned short* __restrict__ Khi, const unsigned short* __restrict__ Klo,
    const unsigned short* __restrict__ Vthi, const unsigned short* __restrict__ Vtlo,
    unsigned short* __restrict__ AOhi, unsigned short* __restrict__ AOlo) {
  __shared__ __align__(16) unsigned short sKh[64 * 64];
  __shared__ __align__(16) unsigned short sKl[64 * 64];
  __shared__ __align__(16) unsigned short sVh[64 * 64];
  __shared__ __align__(16) unsigned short sVl[64 * 64];
  __shared__ __align__(16) unsigned int sPp[4][16][68];  // [wave][l-row][s-col] packed hi|lo

  const int tid = threadIdx.x;
  const int wave = tid >> 6, lane = tid & 63;
  const int quad = lane >> 4, l16 = lane & 15;
  const int lB = blockIdx.x * 64;
  const int h = blockIdx.y, b = blockIdx.z;

  // Q fragments (A-layout); 0.125*log2e folded upstream
  short8 qh[2], ql[2];
  {
    const size_t base = (size_t)(b * cL + lB + wave * 16 + l16) * cD + h * cHD + quad * 8;
    qh[0] = *(const short8*)(qhi + base);
    qh[1] = *(const short8*)(qhi + base + 32);
    ql[0] = *(const short8*)(qlo + base);
    ql[1] = *(const short8*)(qlo + base + 32);
  }

  short8 ones;
#pragma unroll
  for (int i = 0; i < 8; i++) ones[i] = (short)0x3F80;  // bf16 1.0

  f32x4 O[4], dacc;
  float mrow[4];
#pragma unroll
  for (int i = 0; i < 4; i++) {
    O[i] = (f32x4){0.f, 0.f, 0.f, 0.f};
    mrow[i] = -INFINITY;
  }
  dacc = (f32x4){0.f, 0.f, 0.f, 0.f};

  const int srow8 = lane >> 3;        // row within 8-row staging slab
  const int sg = (lane & 7) ^ srow8;  // permuted global granule

  uint4 pk[2][4];  // [slab][Khi,Klo,Vhi,Vlo] prefetch registers
  auto prefetch = [&](int s0) {
#pragma unroll
    for (int c = 0; c < 2; c++) {
      const int j = wave * 2 + c;
      const int r = j * 8 + srow8;
      const size_t ka = (size_t)(b * cS + s0 + r) * cD + h * cHD + sg * 8;
      const size_t va = (size_t)(b * cD + h * cHD + r) * cS + s0 + sg * 8;
      pk[c][0] = *(const uint4*)(Khi + ka);
      pk[c][1] = *(const uint4*)(Klo + ka);
      pk[c][2] = *(const uint4*)(Vthi + va);
      pk[c][3] = *(const uint4*)(Vtlo + va);
    }
  };

  prefetch(0);
  for (int s0 = 0; s0 < cS; s0 += 64) {
    __syncthreads();  // all waves done reading LDS from prior chunk
#pragma unroll
    for (int c = 0; c < 2; c++) {
      const int j = wave * 2 + c;
      *(uint4*)&sKh[j * 512 + lane * 8] = pk[c][0];
      *(uint4*)&sKl[j * 512 + lane * 8] = pk[c][1];
      *(uint4*)&sVh[j * 512 + lane * 8] = pk[c][2];
      *(uint4*)&sVl[j * 512 + lane * 8] = pk[c][3];
    }
    __syncthreads();
    if (s0 + 64 < cS) prefetch(s0 + 64);  // vmcnt waited at next iter's LDS stores

    // QK^T, 3-term split (exp2 domain)
    f32x4 sc[4];
#pragma unroll
    for (int st = 0; st < 4; st++) sc[st] = (f32x4){0.f, 0.f, 0.f, 0.f};
#pragma unroll
    for (int st = 0; st < 4; st++) {
      const int srw = st * 16 + l16;
#pragma unroll
      for (int ks = 0; ks < 2; ks++) {
        const int slot = (ks * 4 + quad) ^ (srw & 7);
        const short8 kfh = *(const short8*)&sKh[srw * 64 + slot * 8];
        const short8 kfl = *(const short8*)&sKl[srw * 64 + slot * 8];
        sc[st] = MFMA16(qh[ks], kfh, sc[st]);
        sc[st] = MFMA16(ql[ks], kfh, sc[st]);
        sc[st] = MFMA16(qh[ks], kfl, sc[st]);
      }
    }

    // online max (C-layout: row=quad*4+r, col=st*16+l16)
    float mx[4], al[4];
#pragma unroll
    for (int r = 0; r < 4; r++)
      mx[r] = fmaxf(fmaxf(sc[0][r], sc[1][r]), fmaxf(sc[2][r], sc[3][r]));
#pragma unroll
    for (int o = 1; o < 16; o <<= 1)
#pragma unroll
      for (int r = 0; r < 4; r++) mx[r] = fmaxf(mx[r], __shfl_xor(mx[r], o, 64));
#pragma unroll
    for (int r = 0; r < 4; r++) {
      const float mn = fmaxf(mrow[r], mx[r]);
      al[r] = __builtin_amdgcn_exp2f(mrow[r] - mn);
      mrow[r] = mn;
    }
    // P = exp2(sc - m), packed hi/lo -> per-wave LDS
#pragma unroll
    for (int st = 0; st < 4; st++)
#pragma unroll
      for (int r = 0; r < 4; r++) {
        const float p = __builtin_amdgcn_exp2f(sc[st][r] - mrow[r]);
        sPp[wave][quad * 4 + r][st * 16 + l16] = pack_split(p);
      }
    // rescale running state
#pragma unroll
    for (int dt = 0; dt < 4; dt++)
#pragma unroll
      for (int r = 0; r < 4; r++) O[dt][r] *= al[r];
#pragma unroll
    for (int r = 0; r < 4; r++) dacc[r] *= al[r];

    // P fragments (A-layout), wave-local (same-wave LDS ordering)
    short8 pfh[2], pfl[2];
#pragma unroll
    for (int ss = 0; ss < 2; ss++) {
      const uint4 pa = *(const uint4*)&sPp[wave][l16][ss * 32 + quad * 8];
      const uint4 pb = *(const uint4*)&sPp[wave][l16][ss * 32 + quad * 8 + 4];
      unpack8(pa, pb, pfh[ss], pfl[ss]);
    }
    // PV, 3-term split
#pragma unroll
    for (int dt = 0; dt < 4; dt++) {
      const int drw = dt * 16 + l16;
#pragma unroll
      for (int ss = 0; ss < 2; ss++) {
        const int slot = (ss * 4 + quad) ^ (drw & 7);
        const short8 vfh = *(const short8*)&sVh[drw * 64 + slot * 8];
        const short8 vfl = *(const short8*)&sVl[drw * 64 + slot * 8];
        O[dt] = MFMA16(pfh[ss], vfh, O[dt]);
        O[dt] = MFMA16(pfh[ss], vfl, O[dt]);
        O[dt] = MFMA16(pfl[ss], vfh, O[dt]);
      }
    }
    // denominator via ones-MFMA (replaces shuffle sum tree)
    dacc = MFMA16(pfh[0], ones, dacc);
    dacc = MFMA16(pfl[0], ones, dacc);
    dacc = MFMA16(pfh[1], ones, dacc);
    dacc = MFMA16(pfl[1], ones, dacc);
  }

  // epilogue: row = quad*4+r, col = dt*16+l16; dacc col-replicated
  float inv[4];
#pragma unroll
  for (int r = 0; r < 4; r++) inv[r] = 1.f / dacc[r];
#pragma unroll
  for (int dt = 0; dt < 4; dt++)
#pragma unroll
    for (int r = 0; r < 4; r++) {
      const float v = O[dt][r] * inv[r];
      const unsigned short hi = f2bf(v);
      const size_t l = (size_t)(b * cL + lB + wave * 16 + quad * 4 + r);
      const size_t idx = l * cD + h * cHD + dt * 16 + l16;
      AOhi[idx] = hi;
      AOlo[idx] = f2bf(v - bf2f(hi));
    }
}

}  // namespace

extern "C" void kernel_launch(void* const* d_in, const int* in_sizes, int n_in,
                              void* d_out, int out_size, void* d_ws, size_t ws_size,
                              hipStream_t stream) {
  (void)in_sizes; (void)n_in; (void)out_size; (void)ws_size;
  const float* x_q = (const float*)d_in[0];
  const int* x_idx = (const int*)d_in[1];
  const float* E_slots = (const float*)d_in[2];
  const float* rhos = (const float*)d_in[3];
  const float* C_seq = (const float*)d_in[4];
  const float* Wq = (const float*)d_in[5];
  const float* Wk = (const float*)d_in[6];
  const float* Wv = (const float*)d_in[7];
  const float* Wo = (const float*)d_in[8];
  const float* Wpe = (const float*)d_in[9];
  const float* ln_kv_g = (const float*)d_in[10];
  const float* ln_kv_b = (const float*)d_in[11];
  const float* ln_q_g = (const float*)d_in[12];
  const float* ln_q_b = (const float*)d_in[13];
  float* out = (float*)d_out;

  float* ws = (float*)d_ws;
  unsigned short* memhi = (unsigned short*)(ws + 0);
  unsigned short* memlo = (unsigned short*)(ws + 262144);
  unsigned short* Wkhi = (unsigned short*)(ws + 524288);
  unsigned short* Wklo = (unsigned short*)(ws + 1048576);
  unsigned short* Wvhi = (unsigned short*)(ws + 1572864);
  unsigned short* Wvlo = (unsigned short*)(ws + 2097152);
  float* gkv = ws + 2621440;
  unsigned short* qhi = (unsigned short*)(ws + 0);          // overlay (dead before Q GEMM)
  unsigned short* qlo = (unsigned short*)(ws + 2097152);
  unsigned short* Wqhi = (unsigned short*)(ws + 4718592);
  unsigned short* Wqlo = (unsigned short*)(ws + 5242880);
  unsigned short* Wohi = (unsigned short*)(ws + 5767168);
  unsigned short* Wolo = (unsigned short*)(ws + 6291456);
  float* Ek = ws + 6815744;
  float* Ev = ws + 7340032;
  unsigned short* Yhi = (unsigned short*)(ws + 7864320);
  unsigned short* Ylo = (unsigned short*)(ws + 9961472);
  unsigned short* AOhi = (unsigned short*)(ws + 7864320);   // overlay Y (dead after Q GEMM)
  unsigned short* AOlo = (unsigned short*)(ws + 9961472);
  unsigned short* Khi = (unsigned short*)(ws + 12058624);
  unsigned short* Klo = (unsigned short*)(ws + 14155776);
  unsigned short* Vthi = (unsigned short*)(ws + 16252928);
  unsigned short* Vtlo = (unsigned short*)(ws + 18350080);

  constexpr float kQScale = 0.125f * 1.44269504088896340736f;  // fold 1/sqrt(HD) * log2(e)

  wsplit_kernel<<<2048, 256, 0, stream>>>(Wq, Wk, Wv, Wo, Wqhi, Wqlo, Wkhi, Wklo,
                                          Wvhi, Wvlo, Wohi, Wolo);
  ln_slots_kernel<<<cNSLOT, 256, 0, stream>>>(E_slots, ln_kv_g, ln_kv_b, memhi, memlo);
  gemm_sp_kernel<0><<<dim3(8, 4, 2), 512, 0, stream>>>(
      memhi, memlo, Wkhi, Wklo, Wvhi, Wvlo, Ek, Ev, nullptr, nullptr, cNSLOT, cD, cD, 1.f);
  gatekv_kernel<<<cS, 256, 0, stream>>>(rhos, Wpe, gkv);
  prep_k_kernel<<<2048, 256, 0, stream>>>(Ek, gkv, x_idx, Khi, Klo);
  prep_vt_kernel<<<dim3(cS / 64, cD / 64, cB), 256, 0, stream>>>(Ev, gkv, x_idx, Vthi, Vtlo);
  qgate_ln_kernel<<<cB * cL, 256, 0, stream>>>(x_q, C_seq, Wpe, ln_q_g, ln_q_b, Yhi, Ylo);
  gemm_sp_kernel<1><<<dim3(8, 32, 1), 512, 0, stream>>>(
      Yhi, Ylo, Wqhi, Wqlo, Wqhi, Wqlo, nullptr, nullptr, qhi, qlo, cB * cL, cD, cD, kQScale);
  attn_mfma_kernel<<<dim3(cL / 64, cH, cB), 256, 0, stream>>>(qhi, qlo, Khi, Klo, Vthi, Vtlo,
                                                              AOhi, AOlo);
  gemm_sp_kernel<0><<<dim3(8, 32, 1), 512, 0, stream>>>(
      AOhi, AOlo, Wohi, Wolo, Wohi, Wolo, out, out, nullptr, nullptr, cB * cL, cD, cD, 1.f);
}

// Round 5
// 402.910 us; speedup vs baseline: 1.4017x; 1.4017x over previous
//
#include <hip/hip_runtime.h>
#include <cmath>
#include <cstddef>

namespace {

constexpr int cB = 2, cL = 2048, cS = 2048, cD = 1024, cH = 16, cNS = 8, cNSLOT = 512, cHD = 64;

typedef __attribute__((ext_vector_type(8))) short short8;
typedef __attribute__((ext_vector_type(4))) float f32x4;

#define MFMA16(a, b, c) __builtin_amdgcn_mfma_f32_16x16x32_bf16((a), (b), (c), 0, 0, 0)

__device__ __forceinline__ float sigmoidf_(float x) { return 1.f / (1.f + __expf(-x)); }

__device__ __forceinline__ unsigned short f2bf(float x) {
  union { float f; unsigned u; } c; c.f = x;
  unsigned r = c.u + 0x7FFFu + ((c.u >> 16) & 1u);
  return (unsigned short)(r >> 16);
}
__device__ __forceinline__ float bf2f(unsigned short h) {
  union { unsigned u; float f; } c; c.u = ((unsigned)h) << 16;
  return c.f;
}

// truncation hi-split + RNE lo-split, packed (lo<<16 | hi) in one uint. 5 VALU.
__device__ __forceinline__ unsigned pack_split(float v) {
  union { float f; unsigned u; } c; c.f = v;
  const unsigned rh = c.u & 0xffff0000u;
  union { float f; unsigned u; } d; d.f = v - __uint_as_float(rh);
  const unsigned t = d.u + 0x7fffu + ((d.u >> 16) & 1u);
  return __builtin_amdgcn_perm(t, c.u, 0x07060302u);
}

__device__ __forceinline__ void unpack8(const uint4 a, const uint4 b, short8& ph, short8& pl) {
  const unsigned p[8] = {a.x, a.y, a.z, a.w, b.x, b.y, b.z, b.w};
  union { unsigned u[4]; short8 s; } H, L;
#pragma unroll
  for (int i = 0; i < 4; i++) {
    H.u[i] = __builtin_amdgcn_perm(p[2 * i + 1], p[2 * i], 0x05040100u);
    L.u[i] = __builtin_amdgcn_perm(p[2 * i + 1], p[2 * i], 0x07060302u);
  }
  ph = H.s;
  pl = L.s;
}

// async global->LDS 16B per lane. lds ptr must be wave-uniform base; HW writes base + lane*16.
__device__ __forceinline__ void async16(const void* g, void* l) {
  __builtin_amdgcn_global_load_lds((const __attribute__((address_space(1))) void*)g,
                                   (__attribute__((address_space(3))) void*)l, 16, 0, 0);
}

// ---------------- weight split: 4 matrices of 1M floats -> hi/lo bf16 ----------------
__global__ __launch_bounds__(256) void wsplit_kernel(
    const float* __restrict__ Wq, const float* __restrict__ Wk,
    const float* __restrict__ Wv, const float* __restrict__ Wo,
    unsigned short* __restrict__ Wqh, unsigned short* __restrict__ Wql,
    unsigned short* __restrict__ Wkh, unsigned short* __restrict__ Wkl,
    unsigned short* __restrict__ Wvh, unsigned short* __restrict__ Wvl,
    unsigned short* __restrict__ Woh, unsigned short* __restrict__ Wol) {
  const int wid = blockIdx.x >> 9;  // 512 blocks per weight
  const size_t off = ((size_t)(blockIdx.x & 511) * 256 + threadIdx.x) * 8;
  const float* src = wid == 0 ? Wq : wid == 1 ? Wk : wid == 2 ? Wv : Wo;
  unsigned short* dh = wid == 0 ? Wqh : wid == 1 ? Wkh : wid == 2 ? Wvh : Woh;
  unsigned short* dl = wid == 0 ? Wql : wid == 1 ? Wkl : wid == 2 ? Wvl : Wol;
  const float4 a = *(const float4*)(src + off);
  const float4 b = *(const float4*)(src + off + 4);
  float v[8] = {a.x, a.y, a.z, a.w, b.x, b.y, b.z, b.w};
  unsigned short h8[8], l8[8];
#pragma unroll
  for (int j = 0; j < 8; j++) {
    h8[j] = f2bf(v[j]);
    l8[j] = f2bf(v[j] - bf2f(h8[j]));
  }
  *(uint4*)(dh + off) = *(uint4*)h8;
  *(uint4*)(dl + off) = *(uint4*)l8;
}

// ---------------- LayerNorm of E_slots rows -> hi/lo bf16 ----------------
__global__ __launch_bounds__(256) void ln_slots_kernel(const float* __restrict__ E,
                                                       const float* __restrict__ gamma,
                                                       const float* __restrict__ beta,
                                                       unsigned short* __restrict__ mh,
                                                       unsigned short* __restrict__ ml) {
  __shared__ float rbuf[8];
  const int row = blockIdx.x;
  const int tid = threadIdx.x;
  const int d0 = tid * 4;
  const float4 x = *(const float4*)(E + (size_t)row * cD + d0);
  float s1 = x.x + x.y + x.z + x.w;
  float s2 = x.x * x.x + x.y * x.y + x.z * x.z + x.w * x.w;
#pragma unroll
  for (int o = 32; o > 0; o >>= 1) { s1 += __shfl_xor(s1, o, 64); s2 += __shfl_xor(s2, o, 64); }
  if ((tid & 63) == 0) { rbuf[tid >> 6] = s1; rbuf[4 + (tid >> 6)] = s2; }
  __syncthreads();
  s1 = rbuf[0] + rbuf[1] + rbuf[2] + rbuf[3];
  s2 = rbuf[4] + rbuf[5] + rbuf[6] + rbuf[7];
  const float mean = s1 * (1.f / cD);
  const float var = s2 * (1.f / cD) - mean * mean;
  const float inv = rsqrtf(var + 1e-5f);
  const float4 g = *(const float4*)(gamma + d0);
  const float4 b = *(const float4*)(beta + d0);
  float y[4];
  y[0] = (x.x - mean) * inv * g.x + b.x;
  y[1] = (x.y - mean) * inv * g.y + b.y;
  y[2] = (x.z - mean) * inv * g.z + b.z;
  y[3] = (x.w - mean) * inv * g.w + b.w;
  unsigned short h4[4], l4[4];
#pragma unroll
  for (int j = 0; j < 4; j++) {
    h4[j] = f2bf(y[j]);
    l4[j] = f2bf(y[j] - bf2f(h4[j]));
  }
  *(uint2*)(mh + (size_t)row * cD + d0) = *(uint2*)h4;
  *(uint2*)(ml + (size_t)row * cD + d0) = *(uint2*)l4;
}

// ---------------- Q-side: Y = LN(x_q * SiLU(C_seq @ Wpe^T)) -> hi/lo bf16 ----------------
__global__ __launch_bounds__(256) void qgate_ln_kernel(const float* __restrict__ xq,
                                                       const float* __restrict__ Cseq,
                                                       const float* __restrict__ Wpe,
                                                       const float* __restrict__ gamma,
                                                       const float* __restrict__ beta,
                                                       unsigned short* __restrict__ Yh,
                                                       unsigned short* __restrict__ Yl) {
  __shared__ float sC[cNS];
  __shared__ float rbuf[8];
  const int row = blockIdx.x;
  const int tid = threadIdx.x;
  if (tid < cNS) sC[tid] = Cseq[(size_t)row * cNS + tid];
  __syncthreads();
  const int d0 = tid * 4;
  const float4 x = *(const float4*)(xq + (size_t)row * cD + d0);
  float y[4];
  float s1 = 0.f, s2 = 0.f;
#pragma unroll
  for (int j = 0; j < 4; j++) {
    const float* wr = Wpe + (size_t)(d0 + j) * cNS;
    float gs = 0.f;
#pragma unroll
    for (int m = 0; m < cNS; m++) gs += sC[m] * wr[m];
    const float val = ((const float*)&x)[j] * gs * sigmoidf_(gs);
    y[j] = val;
    s1 += val;
    s2 += val * val;
  }
#pragma unroll
  for (int o = 32; o > 0; o >>= 1) { s1 += __shfl_xor(s1, o, 64); s2 += __shfl_xor(s2, o, 64); }
  if ((tid & 63) == 0) { rbuf[tid >> 6] = s1; rbuf[4 + (tid >> 6)] = s2; }
  __syncthreads();
  s1 = rbuf[0] + rbuf[1] + rbuf[2] + rbuf[3];
  s2 = rbuf[4] + rbuf[5] + rbuf[6] + rbuf[7];
  const float mean = s1 * (1.f / cD);
  const float var = s2 * (1.f / cD) - mean * mean;
  const float inv = rsqrtf(var + 1e-5f);
  const float4 g = *(const float4*)(gamma + d0);
  const float4 b = *(const float4*)(beta + d0);
  float z[4];
  z[0] = (y[0] - mean) * inv * g.x + b.x;
  z[1] = (y[1] - mean) * inv * g.y + b.y;
  z[2] = (y[2] - mean) * inv * g.z + b.z;
  z[3] = (y[3] - mean) * inv * g.w + b.w;
  unsigned short h4[4], l4[4];
#pragma unroll
  for (int j = 0; j < 4; j++) {
    h4[j] = f2bf(z[j]);
    l4[j] = f2bf(z[j] - bf2f(h4[j]));
  }
  *(uint2*)(Yh + (size_t)row * cD + d0) = *(uint2*)h4;
  *(uint2*)(Yl + (size_t)row * cD + d0) = *(uint2*)l4;
}

// ---------------- gate_kv[s, d] = SiLU( sum_m rho_m^(S-1-s) * Wpe[d, m] ) ----------------
__global__ __launch_bounds__(256) void gatekv_kernel(const float* __restrict__ rhos,
                                                     const float* __restrict__ Wpe,
                                                     float* __restrict__ gkv) {
  __shared__ float sC[cNS];
  const int s = blockIdx.x;
  const int tid = threadIdx.x;
  if (tid < cNS) {
    const float age = (float)(cS - 1 - s);
    sC[tid] = __expf(age * __logf(rhos[tid]));
  }
  __syncthreads();
  const int d0 = tid * 4;
  float4 o4;
#pragma unroll
  for (int j = 0; j < 4; j++) {
    const float* wr = Wpe + (size_t)(d0 + j) * cNS;
    float gs = 0.f;
#pragma unroll
    for (int m = 0; m < cNS; m++) gs += sC[m] * wr[m];
    ((float*)&o4)[j] = gs * sigmoidf_(gs);
  }
  *(float4*)(gkv + (size_t)s * cD + d0) = o4;
}

// ---------------- split-bf16 MFMA GEMM: C[M,N] = A[M,K] @ W[N,K]^T ----------------
// 128x128 tile, BK=32, 512 thr (8 waves, 4x2), double-buffered LDS w/ async prefetch.
// blockIdx.z selects (W,C) pair -> fuses K/V projections into one dispatch.
// MODE 0: fp32 out. MODE 1: scale then hi/lo bf16 split out.
template <int MODE>
__global__ __launch_bounds__(512) void gemm_sp_kernel(
    const unsigned short* __restrict__ Ahi, const unsigned short* __restrict__ Alo,
    const unsigned short* __restrict__ Whi0, const unsigned short* __restrict__ Wlo0,
    const unsigned short* __restrict__ Whi1, const unsigned short* __restrict__ Wlo1,
    float* __restrict__ Cf0, float* __restrict__ Cf1,
    unsigned short* __restrict__ Chi, unsigned short* __restrict__ Clo,
    int M, int N, int K, float scale) {
  __shared__ __align__(16) unsigned short sAh[2][128 * 32];
  __shared__ __align__(16) unsigned short sAl[2][128 * 32];
  __shared__ __align__(16) unsigned short sBh[2][128 * 32];
  __shared__ __align__(16) unsigned short sBl[2][128 * 32];
  const unsigned short* Whi = blockIdx.z ? Whi1 : Whi0;
  const unsigned short* Wlo = blockIdx.z ? Wlo1 : Wlo0;
  float* Cf = blockIdx.z ? Cf1 : Cf0;
  const int tid = threadIdx.x;
  const int wave = tid >> 6, lane = tid & 63;
  const int quad = lane >> 4, l16 = lane & 15;
  const int m0 = blockIdx.y * 128, n0 = blockIdx.x * 128;
  const int wy = wave >> 1, wx = wave & 1;           // wave tile: 32(m) x 64(n)
  const int srow = lane >> 2;                        // row within 16-row staging inst
  const int sg = (lane & 3) ^ ((lane >> 3) & 3);     // permuted global granule

  f32x4 acc[2][4];
#pragma unroll
  for (int i = 0; i < 2; i++)
#pragma unroll
    for (int j = 0; j < 4; j++) acc[i][j] = (f32x4){0.f, 0.f, 0.f, 0.f};

  auto stage = [&](int buf, int k0) {
    const int row = wave * 16 + srow;
    const size_t ga = (size_t)(m0 + row) * K + k0 + sg * 8;
    const size_t gb = (size_t)(n0 + row) * K + k0 + sg * 8;
    async16(Ahi + ga, &sAh[buf][wave * 512]);
    async16(Alo + ga, &sAl[buf][wave * 512]);
    async16(Whi + gb, &sBh[buf][wave * 512]);
    async16(Wlo + gb, &sBl[buf][wave * 512]);
  };

  stage(0, 0);
  __syncthreads();
  const int aswz = (l16 >> 1) & 3;
  int buf = 0;
  for (int k0 = 0; k0 < K; k0 += 32, buf ^= 1) {
    if (k0 + 32 < K) stage(buf ^ 1, k0 + 32);  // drains at iter-end barrier
    short8 bh[4], bl4[4];
#pragma unroll
    for (int t = 0; t < 4; t++) {
      const int br = (wx * 64 + t * 16 + l16) * 32 + ((quad ^ aswz) * 8);
      bh[t] = *(const short8*)&sBh[buf][br];
      bl4[t] = *(const short8*)&sBl[buf][br];
    }
#pragma unroll
    for (int ti = 0; ti < 2; ti++) {
      const int ar = (wy * 32 + ti * 16 + l16) * 32 + ((quad ^ aswz) * 8);
      const short8 ah = *(const short8*)&sAh[buf][ar];
      const short8 al4 = *(const short8*)&sAl[buf][ar];
#pragma unroll
      for (int tj = 0; tj < 4; tj++) {
        acc[ti][tj] = MFMA16(ah, bh[tj], acc[ti][tj]);
        acc[ti][tj] = MFMA16(al4, bh[tj], acc[ti][tj]);
        acc[ti][tj] = MFMA16(ah, bl4[tj], acc[ti][tj]);
      }
    }
    __syncthreads();
  }

#pragma unroll
  for (int ti = 0; ti < 2; ti++)
#pragma unroll
    for (int tj = 0; tj < 4; tj++) {
      const int row = m0 + wy * 32 + ti * 16 + quad * 4;
      const int col = n0 + wx * 64 + tj * 16 + l16;
#pragma unroll
      for (int r = 0; r < 4; r++) {
        const size_t idx = (size_t)(row + r) * N + col;
        if constexpr (MODE == 0) {
          Cf[idx] = acc[ti][tj][r];
        } else {
          const float v = acc[ti][tj][r] * scale;
          const unsigned short hi = f2bf(v);
          Chi[idx] = hi;
          Clo[idx] = f2bf(v - bf2f(hi));
        }
      }
    }
}

// ---------------- prep: K = gather(Ek)*gate, split hi/lo bf16, [B][S][D] ----------------
__global__ __launch_bounds__(256) void prep_k_kernel(const float* __restrict__ Ek,
                                                     const float* __restrict__ gkv,
                                                     const int* __restrict__ xidx,
                                                     unsigned short* __restrict__ Khi,
                                                     unsigned short* __restrict__ Klo) {
  const int t = blockIdx.x * 256 + threadIdx.x;
  const int d0 = (t & 127) * 8;
  const int s = (t >> 7) & (cS - 1);
  const int b = t >> 18;
  const int slot = xidx[b * cS + s];
  const float4 e0 = *(const float4*)(Ek + (size_t)slot * cD + d0);
  const float4 e1 = *(const float4*)(Ek + (size_t)slot * cD + d0 + 4);
  const float4 g0 = *(const float4*)(gkv + (size_t)s * cD + d0);
  const float4 g1 = *(const float4*)(gkv + (size_t)s * cD + d0 + 4);
  float v[8] = {e0.x * g0.x, e0.y * g0.y, e0.z * g0.z, e0.w * g0.w,
                e1.x * g1.x, e1.y * g1.y, e1.z * g1.z, e1.w * g1.w};
  unsigned short h8[8], l8[8];
#pragma unroll
  for (int j = 0; j < 8; j++) {
    h8[j] = f2bf(v[j]);
    l8[j] = f2bf(v[j] - bf2f(h8[j]));
  }
  const size_t off = (size_t)(b * cS + s) * cD + d0;
  *(uint4*)(Khi + off) = *(uint4*)h8;
  *(uint4*)(Klo + off) = *(uint4*)l8;
}

// ---------------- prep: Vt[b][d][s] = gather(Ev)*gate, split hi/lo bf16 (transposed) ----------------
__global__ __launch_bounds__(256) void prep_vt_kernel(const float* __restrict__ Ev,
                                                      const float* __restrict__ gkv,
                                                      const int* __restrict__ xidx,
                                                      unsigned short* __restrict__ Vthi,
                                                      unsigned short* __restrict__ Vtlo) {
  __shared__ float tile[64][65];
  const int s0 = blockIdx.x * 64, d0 = blockIdx.y * 64, b = blockIdx.z;
  const int tid = threadIdx.x;
  const int sl = tid >> 4;
  const int dl = (tid & 15) * 4;
#pragma unroll
  for (int it = 0; it < 4; it++) {
    const int s = s0 + sl + it * 16;
    const int slot = xidx[b * cS + s];
    const float4 e = *(const float4*)(Ev + (size_t)slot * cD + d0 + dl);
    const float4 g = *(const float4*)(gkv + (size_t)s * cD + d0 + dl);
    tile[sl + it * 16][dl + 0] = e.x * g.x;
    tile[sl + it * 16][dl + 1] = e.y * g.y;
    tile[sl + it * 16][dl + 2] = e.z * g.z;
    tile[sl + it * 16][dl + 3] = e.w * g.w;
  }
  __syncthreads();
  const int dr = tid >> 3;
  const int sc = (tid & 7) * 8;
#pragma unroll
  for (int it = 0; it < 2; it++) {
    const int d = d0 + dr + it * 32;
    unsigned short h8[8], l8[8];
#pragma unroll
    for (int j = 0; j < 8; j++) {
      const float v = tile[sc + j][dr + it * 32];
      h8[j] = f2bf(v);
      l8[j] = f2bf(v - bf2f(h8[j]));
    }
    const size_t off = (size_t)(b * cD + d) * cS + s0 + sc;
    *(uint4*)(Vthi + off) = *(uint4*)h8;
    *(uint4*)(Vtlo + off) = *(uint4*)l8;
  }
}

// ---------------- MFMA flash attention v4 ----------------
// grid (L/64, H, B) = 1024 blocks, 256 thr = 4 waves, wave owns 16 l-rows. s-chunk 64.
// Register double-buffer with NAMED uint4 scalars (no array/lambda -> no scratch spill);
// unconditional wrapped prefetch (no conditional def across backedge).
__global__ __launch_bounds__(256, 3) void attn_mfma_kernel(
    const unsigned short* __restrict__ qhi, const unsigned short* __restrict__ qlo,
    const unsigned short* __restrict__ Khi, const unsigned short* __restrict__ Klo,
    const unsigned short* __restrict__ Vthi, const unsigned short* __restrict__ Vtlo,
    unsigned short* __restrict__ AOhi, unsigned short* __restrict__ AOlo) {
  __shared__ __align__(16) unsigned short sKh[64 * 64];
  __shared__ __align__(16) unsigned short sKl[64 * 64];
  __shared__ __align__(16) unsigned short sVh[64 * 64];
  __shared__ __align__(16) unsigned short sVl[64 * 64];
  __shared__ __align__(16) unsigned int sPp[4][16][68];  // [wave][l-row][s-col] packed hi|lo

  const int tid = threadIdx.x;
  const int wave = tid >> 6, lane = tid & 63;
  const int quad = lane >> 4, l16 = lane & 15;
  const int lB = blockIdx.x * 64;
  const int h = blockIdx.y, b = blockIdx.z;

  // Q fragments (A-layout); 0.125*log2e folded upstream
  short8 qh[2], ql[2];
  {
    const size_t base = (size_t)(b * cL + lB + wave * 16 + l16) * cD + h * cHD + quad * 8;
    qh[0] = *(const short8*)(qhi + base);
    qh[1] = *(const short8*)(qhi + base + 32);
    ql[0] = *(const short8*)(qlo + base);
    ql[1] = *(const short8*)(qlo + base + 32);
  }

  short8 ones;
#pragma unroll
  for (int i = 0; i < 8; i++) ones[i] = (short)0x3F80;  // bf16 1.0

  f32x4 O[4], dacc;
  float mrow[4];
#pragma unroll
  for (int i = 0; i < 4; i++) {
    O[i] = (f32x4){0.f, 0.f, 0.f, 0.f};
    mrow[i] = -INFINITY;
  }
  dacc = (f32x4){0.f, 0.f, 0.f, 0.f};

  const int srow8 = lane >> 3;        // row within 8-row staging slab
  const int sg = (lane & 7) ^ srow8;  // permuted global granule

  // per-thread row/col constants for the two staging slabs
  const int r0 = (wave * 2 + 0) * 8 + srow8;
  const int r1 = (wave * 2 + 1) * 8 + srow8;
  const size_t kb0 = (size_t)(b * cS + r0) * cD + h * cHD + sg * 8;  // + s*cD
  const size_t kb1 = (size_t)(b * cS + r1) * cD + h * cHD + sg * 8;
  const size_t vb0 = (size_t)(b * cD + h * cHD + r0) * cS + sg * 8;  // + s
  const size_t vb1 = (size_t)(b * cD + h * cHD + r1) * cS + sg * 8;

  // named prefetch registers (NO arrays -> stay in VGPRs)
  uint4 k0h, k0l, v0h, v0l, k1h, k1l, v1h, v1l;
  k0h = *(const uint4*)(Khi + kb0);
  k0l = *(const uint4*)(Klo + kb0);
  v0h = *(const uint4*)(Vthi + vb0);
  v0l = *(const uint4*)(Vtlo + vb0);
  k1h = *(const uint4*)(Khi + kb1);
  k1l = *(const uint4*)(Klo + kb1);
  v1h = *(const uint4*)(Vthi + vb1);
  v1l = *(const uint4*)(Vtlo + vb1);

  const int j0 = wave * 2, j1 = wave * 2 + 1;

  for (int s0 = 0; s0 < cS; s0 += 64) {
    __syncthreads();  // all waves done reading LDS from prior chunk
    *(uint4*)&sKh[j0 * 512 + lane * 8] = k0h;
    *(uint4*)&sKl[j0 * 512 + lane * 8] = k0l;
    *(uint4*)&sVh[j0 * 512 + lane * 8] = v0h;
    *(uint4*)&sVl[j0 * 512 + lane * 8] = v0l;
    *(uint4*)&sKh[j1 * 512 + lane * 8] = k1h;
    *(uint4*)&sKl[j1 * 512 + lane * 8] = k1l;
    *(uint4*)&sVh[j1 * 512 + lane * 8] = v1h;
    *(uint4*)&sVl[j1 * 512 + lane * 8] = v1l;
    __syncthreads();

    // unconditional wrapped prefetch of next chunk (issues now, used next iter)
    {
      const int sn = (s0 + 64) & (cS - 1);
      const size_t kc = (size_t)sn * cD;
      k0h = *(const uint4*)(Khi + kb0 + kc);
      k0l = *(const uint4*)(Klo + kb0 + kc);
      v0h = *(const uint4*)(Vthi + vb0 + sn);
      v0l = *(const uint4*)(Vtlo + vb0 + sn);
      k1h = *(const uint4*)(Khi + kb1 + kc);
      k1l = *(const uint4*)(Klo + kb1 + kc);
      v1h = *(const uint4*)(Vthi + vb1 + sn);
      v1l = *(const uint4*)(Vtlo + vb1 + sn);
    }

    // QK^T, 3-term split (exp2 domain)
    f32x4 sc[4];
#pragma unroll
    for (int st = 0; st < 4; st++) sc[st] = (f32x4){0.f, 0.f, 0.f, 0.f};
#pragma unroll
    for (int st = 0; st < 4; st++) {
      const int srw = st * 16 + l16;
#pragma unroll
      for (int ks = 0; ks < 2; ks++) {
        const int slot = (ks * 4 + quad) ^ (srw & 7);
        const short8 kfh = *(const short8*)&sKh[srw * 64 + slot * 8];
        const short8 kfl = *(const short8*)&sKl[srw * 64 + slot * 8];
        sc[st] = MFMA16(qh[ks], kfh, sc[st]);
        sc[st] = MFMA16(ql[ks], kfh, sc[st]);
        sc[st] = MFMA16(qh[ks], kfl, sc[st]);
      }
    }

    // online max (C-layout: row=quad*4+r, col=st*16+l16)
    float mx[4], al[4];
#pragma unroll
    for (int r = 0; r < 4; r++)
      mx[r] = fmaxf(fmaxf(sc[0][r], sc[1][r]), fmaxf(sc[2][r], sc[3][r]));
#pragma unroll
    for (int o = 1; o < 16; o <<= 1)
#pragma unroll
      for (int r = 0; r < 4; r++) mx[r] = fmaxf(mx[r], __shfl_xor(mx[r], o, 64));
#pragma unroll
    for (int r = 0; r < 4; r++) {
      const float mn = fmaxf(mrow[r], mx[r]);
      al[r] = __builtin_amdgcn_exp2f(mrow[r] - mn);
      mrow[r] = mn;
    }
    // P = exp2(sc - m), packed hi/lo -> per-wave LDS
#pragma unroll
    for (int st = 0; st < 4; st++)
#pragma unroll
      for (int r = 0; r < 4; r++) {
        const float p = __builtin_amdgcn_exp2f(sc[st][r] - mrow[r]);
        sPp[wave][quad * 4 + r][st * 16 + l16] = pack_split(p);
      }
    // rescale running state
#pragma unroll
    for (int dt = 0; dt < 4; dt++)
#pragma unroll
      for (int r = 0; r < 4; r++) O[dt][r] *= al[r];
#pragma unroll
    for (int r = 0; r < 4; r++) dacc[r] *= al[r];

    // P fragments (A-layout), wave-local (same-wave LDS ordering)
    short8 pfh[2], pfl[2];
#pragma unroll
    for (int ss = 0; ss < 2; ss++) {
      const uint4 pa = *(const uint4*)&sPp[wave][l16][ss * 32 + quad * 8];
      const uint4 pb = *(const uint4*)&sPp[wave][l16][ss * 32 + quad * 8 + 4];
      unpack8(pa, pb, pfh[ss], pfl[ss]);
    }
    // PV, 3-term split
#pragma unroll
    for (int dt = 0; dt < 4; dt++) {
      const int drw = dt * 16 + l16;
#pragma unroll
      for (int ss = 0; ss < 2; ss++) {
        const int slot = (ss * 4 + quad) ^ (drw & 7);
        const short8 vfh = *(const short8*)&sVh[drw * 64 + slot * 8];
        const short8 vfl = *(const short8*)&sVl[drw * 64 + slot * 8];
        O[dt] = MFMA16(pfh[ss], vfh, O[dt]);
        O[dt] = MFMA16(pfh[ss], vfl, O[dt]);
        O[dt] = MFMA16(pfl[ss], vfh, O[dt]);
      }
    }
    // denominator via ones-MFMA (replaces shuffle sum tree)
    dacc = MFMA16(pfh[0], ones, dacc);
    dacc = MFMA16(pfl[0], ones, dacc);
    dacc = MFMA16(pfh[1], ones, dacc);
    dacc = MFMA16(pfl[1], ones, dacc);
  }

  // epilogue: row = quad*4+r, col = dt*16+l16; dacc col-replicated
  float inv[4];
#pragma unroll
  for (int r = 0; r < 4; r++) inv[r] = 1.f / dacc[r];
#pragma unroll
  for (int dt = 0; dt < 4; dt++)
#pragma unroll
    for (int r = 0; r < 4; r++) {
      const float v = O[dt][r] * inv[r];
      const unsigned short hi = f2bf(v);
      const size_t l = (size_t)(b * cL + lB + wave * 16 + quad * 4 + r);
      const size_t idx = l * cD + h * cHD + dt * 16 + l16;
      AOhi[idx] = hi;
      AOlo[idx] = f2bf(v - bf2f(hi));
    }
}

}  // namespace

extern "C" void kernel_launch(void* const* d_in, const int* in_sizes, int n_in,
                              void* d_out, int out_size, void* d_ws, size_t ws_size,
                              hipStream_t stream) {
  (void)in_sizes; (void)n_in; (void)out_size; (void)ws_size;
  const float* x_q = (const float*)d_in[0];
  const int* x_idx = (const int*)d_in[1];
  const float* E_slots = (const float*)d_in[2];
  const float* rhos = (const float*)d_in[3];
  const float* C_seq = (const float*)d_in[4];
  const float* Wq = (const float*)d_in[5];
  const float* Wk = (const float*)d_in[6];
  const float* Wv = (const float*)d_in[7];
  const float* Wo = (const float*)d_in[8];
  const float* Wpe = (const float*)d_in[9];
  const float* ln_kv_g = (const float*)d_in[10];
  const float* ln_kv_b = (const float*)d_in[11];
  const float* ln_q_g = (const float*)d_in[12];
  const float* ln_q_b = (const float*)d_in[13];
  float* out = (float*)d_out;

  float* ws = (float*)d_ws;
  unsigned short* memhi = (unsigned short*)(ws + 0);
  unsigned short* memlo = (unsigned short*)(ws + 262144);
  unsigned short* Wkhi = (unsigned short*)(ws + 524288);
  unsigned short* Wklo = (unsigned short*)(ws + 1048576);
  unsigned short* Wvhi = (unsigned short*)(ws + 1572864);
  unsigned short* Wvlo = (unsigned short*)(ws + 2097152);
  float* gkv = ws + 2621440;
  unsigned short* qhi = (unsigned short*)(ws + 0);          // overlay (dead before Q GEMM)
  unsigned short* qlo = (unsigned short*)(ws + 2097152);
  unsigned short* Wqhi = (unsigned short*)(ws + 4718592);
  unsigned short* Wqlo = (unsigned short*)(ws + 5242880);
  unsigned short* Wohi = (unsigned short*)(ws + 5767168);
  unsigned short* Wolo = (unsigned short*)(ws + 6291456);
  float* Ek = ws + 6815744;
  float* Ev = ws + 7340032;
  unsigned short* Yhi = (unsigned short*)(ws + 7864320);
  unsigned short* Ylo = (unsigned short*)(ws + 9961472);
  unsigned short* AOhi = (unsigned short*)(ws + 7864320);   // overlay Y (dead after Q GEMM)
  unsigned short* AOlo = (unsigned short*)(ws + 9961472);
  unsigned short* Khi = (unsigned short*)(ws + 12058624);
  unsigned short* Klo = (unsigned short*)(ws + 14155776);
  unsigned short* Vthi = (unsigned short*)(ws + 16252928);
  unsigned short* Vtlo = (unsigned short*)(ws + 18350080);

  constexpr float kQScale = 0.125f * 1.44269504088896340736f;  // fold 1/sqrt(HD) * log2(e)

  wsplit_kernel<<<2048, 256, 0, stream>>>(Wq, Wk, Wv, Wo, Wqhi, Wqlo, Wkhi, Wklo,
                                          Wvhi, Wvlo, Wohi, Wolo);
  ln_slots_kernel<<<cNSLOT, 256, 0, stream>>>(E_slots, ln_kv_g, ln_kv_b, memhi, memlo);
  gemm_sp_kernel<0><<<dim3(8, 4, 2), 512, 0, stream>>>(
      memhi, memlo, Wkhi, Wklo, Wvhi, Wvlo, Ek, Ev, nullptr, nullptr, cNSLOT, cD, cD, 1.f);
  gatekv_kernel<<<cS, 256, 0, stream>>>(rhos, Wpe, gkv);
  prep_k_kernel<<<2048, 256, 0, stream>>>(Ek, gkv, x_idx, Khi, Klo);
  prep_vt_kernel<<<dim3(cS / 64, cD / 64, cB), 256, 0, stream>>>(Ev, gkv, x_idx, Vthi, Vtlo);
  qgate_ln_kernel<<<cB * cL, 256, 0, stream>>>(x_q, C_seq, Wpe, ln_q_g, ln_q_b, Yhi, Ylo);
  gemm_sp_kernel<1><<<dim3(8, 32, 1), 512, 0, stream>>>(
      Yhi, Ylo, Wqhi, Wqlo, Wqhi, Wqlo, nullptr, nullptr, qhi, qlo, cB * cL, cD, cD, kQScale);
  attn_mfma_kernel<<<dim3(cL / 64, cH, cB), 256, 0, stream>>>(qhi, qlo, Khi, Klo, Vthi, Vtlo,
                                                              AOhi, AOlo);
  gemm_sp_kernel<0><<<dim3(8, 32, 1), 512, 0, stream>>>(
      AOhi, AOlo, Wohi, Wolo, Wohi, Wolo, out, out, nullptr, nullptr, cB * cL, cD, cD, 1.f);
}

// Round 6
// 351.575 us; speedup vs baseline: 1.6064x; 1.1460x over previous
//
#include <hip/hip_runtime.h>
#include <cmath>
#include <cstddef>

namespace {

constexpr int cB = 2, cL = 2048, cS = 2048, cD = 1024, cH = 16, cNS = 8, cNSLOT = 512, cHD = 64;

typedef __attribute__((ext_vector_type(8))) short short8;
typedef __attribute__((ext_vector_type(4))) float f32x4;

#define MFMA16(a, b, c) __builtin_amdgcn_mfma_f32_16x16x32_bf16((a), (b), (c), 0, 0, 0)

__device__ __forceinline__ float sigmoidf_(float x) { return 1.f / (1.f + __expf(-x)); }

__device__ __forceinline__ unsigned short f2bf(float x) {
  union { float f; unsigned u; } c; c.f = x;
  unsigned r = c.u + 0x7FFFu + ((c.u >> 16) & 1u);
  return (unsigned short)(r >> 16);
}
__device__ __forceinline__ float bf2f(unsigned short h) {
  union { unsigned u; float f; } c; c.u = ((unsigned)h) << 16;
  return c.f;
}

// truncation hi-split + RNE lo-split, packed (lo<<16 | hi) in one uint. 5 VALU.
__device__ __forceinline__ unsigned pack_split(float v) {
  union { float f; unsigned u; } c; c.f = v;
  const unsigned rh = c.u & 0xffff0000u;
  union { float f; unsigned u; } d; d.f = v - __uint_as_float(rh);
  const unsigned t = d.u + 0x7fffu + ((d.u >> 16) & 1u);
  return __builtin_amdgcn_perm(t, c.u, 0x07060302u);
}

__device__ __forceinline__ void unpack8(const uint4 a, const uint4 b, short8& ph, short8& pl) {
  const unsigned p[8] = {a.x, a.y, a.z, a.w, b.x, b.y, b.z, b.w};
  union { unsigned u[4]; short8 s; } H, L;
#pragma unroll
  for (int i = 0; i < 4; i++) {
    H.u[i] = __builtin_amdgcn_perm(p[2 * i + 1], p[2 * i], 0x05040100u);
    L.u[i] = __builtin_amdgcn_perm(p[2 * i + 1], p[2 * i], 0x07060302u);
  }
  ph = H.s;
  pl = L.s;
}

// async global->LDS 16B per lane. lds ptr must be wave-uniform base; HW writes base + lane*16.
__device__ __forceinline__ void async16(const void* g, void* l) {
  __builtin_amdgcn_global_load_lds((const __attribute__((address_space(1))) void*)g,
                                   (__attribute__((address_space(3))) void*)l, 16, 0, 0);
}

// ---------------- fused prep: wsplit | ln_slots | gatekv | qgate_ln ----------------
// grid 8704 x 256: [0,2048) weight split, [2048,2560) ln_slots, [2560,4608) gatekv,
// [4608,8704) qgate_ln.
__global__ __launch_bounds__(256) void prep_all_kernel(
    const float* __restrict__ Wq, const float* __restrict__ Wk,
    const float* __restrict__ Wv, const float* __restrict__ Wo,
    unsigned short* __restrict__ Wqh, unsigned short* __restrict__ Wql,
    unsigned short* __restrict__ Wkh, unsigned short* __restrict__ Wkl,
    unsigned short* __restrict__ Wvh, unsigned short* __restrict__ Wvl,
    unsigned short* __restrict__ Woh, unsigned short* __restrict__ Wol,
    const float* __restrict__ E, const float* __restrict__ lnkv_g,
    const float* __restrict__ lnkv_b, unsigned short* __restrict__ mh,
    unsigned short* __restrict__ ml, const float* __restrict__ rhos,
    const float* __restrict__ Wpe, float* __restrict__ gkv,
    const float* __restrict__ xq, const float* __restrict__ Cseq,
    const float* __restrict__ lnq_g, const float* __restrict__ lnq_b,
    unsigned short* __restrict__ Yh, unsigned short* __restrict__ Yl) {
  __shared__ float sC[cNS];
  __shared__ float rbuf[8];
  const int bid = blockIdx.x;
  const int tid = threadIdx.x;

  if (bid < 2048) {  // ---- weight split ----
    const int wid = bid >> 9;
    const size_t off = ((size_t)(bid & 511) * 256 + tid) * 8;
    const float* src = wid == 0 ? Wq : wid == 1 ? Wk : wid == 2 ? Wv : Wo;
    unsigned short* dh = wid == 0 ? Wqh : wid == 1 ? Wkh : wid == 2 ? Wvh : Woh;
    unsigned short* dl = wid == 0 ? Wql : wid == 1 ? Wkl : wid == 2 ? Wvl : Wol;
    const float4 a = *(const float4*)(src + off);
    const float4 b = *(const float4*)(src + off + 4);
    float v[8] = {a.x, a.y, a.z, a.w, b.x, b.y, b.z, b.w};
    unsigned short h8[8], l8[8];
#pragma unroll
    for (int j = 0; j < 8; j++) {
      h8[j] = f2bf(v[j]);
      l8[j] = f2bf(v[j] - bf2f(h8[j]));
    }
    *(uint4*)(dh + off) = *(uint4*)h8;
    *(uint4*)(dl + off) = *(uint4*)l8;
  } else if (bid < 2560) {  // ---- ln_slots ----
    const int row = bid - 2048;
    const int d0 = tid * 4;
    const float4 x = *(const float4*)(E + (size_t)row * cD + d0);
    float s1 = x.x + x.y + x.z + x.w;
    float s2 = x.x * x.x + x.y * x.y + x.z * x.z + x.w * x.w;
#pragma unroll
    for (int o = 32; o > 0; o >>= 1) { s1 += __shfl_xor(s1, o, 64); s2 += __shfl_xor(s2, o, 64); }
    if ((tid & 63) == 0) { rbuf[tid >> 6] = s1; rbuf[4 + (tid >> 6)] = s2; }
    __syncthreads();
    s1 = rbuf[0] + rbuf[1] + rbuf[2] + rbuf[3];
    s2 = rbuf[4] + rbuf[5] + rbuf[6] + rbuf[7];
    const float mean = s1 * (1.f / cD);
    const float var = s2 * (1.f / cD) - mean * mean;
    const float inv = rsqrtf(var + 1e-5f);
    const float4 g = *(const float4*)(lnkv_g + d0);
    const float4 b = *(const float4*)(lnkv_b + d0);
    float y[4];
    y[0] = (x.x - mean) * inv * g.x + b.x;
    y[1] = (x.y - mean) * inv * g.y + b.y;
    y[2] = (x.z - mean) * inv * g.z + b.z;
    y[3] = (x.w - mean) * inv * g.w + b.w;
    unsigned short h4[4], l4[4];
#pragma unroll
    for (int j = 0; j < 4; j++) {
      h4[j] = f2bf(y[j]);
      l4[j] = f2bf(y[j] - bf2f(h4[j]));
    }
    *(uint2*)(mh + (size_t)row * cD + d0) = *(uint2*)h4;
    *(uint2*)(ml + (size_t)row * cD + d0) = *(uint2*)l4;
  } else if (bid < 4608) {  // ---- gatekv ----
    const int s = bid - 2560;
    if (tid < cNS) {
      const float age = (float)(cS - 1 - s);
      sC[tid] = __expf(age * __logf(rhos[tid]));
    }
    __syncthreads();
    const int d0 = tid * 4;
    float4 o4;
#pragma unroll
    for (int j = 0; j < 4; j++) {
      const float* wr = Wpe + (size_t)(d0 + j) * cNS;
      float gs = 0.f;
#pragma unroll
      for (int m = 0; m < cNS; m++) gs += sC[m] * wr[m];
      ((float*)&o4)[j] = gs * sigmoidf_(gs);
    }
    *(float4*)(gkv + (size_t)s * cD + d0) = o4;
  } else {  // ---- qgate_ln ----
    const int row = bid - 4608;
    if (tid < cNS) sC[tid] = Cseq[(size_t)row * cNS + tid];
    __syncthreads();
    const int d0 = tid * 4;
    const float4 x = *(const float4*)(xq + (size_t)row * cD + d0);
    float y[4];
    float s1 = 0.f, s2 = 0.f;
#pragma unroll
    for (int j = 0; j < 4; j++) {
      const float* wr = Wpe + (size_t)(d0 + j) * cNS;
      float gs = 0.f;
#pragma unroll
      for (int m = 0; m < cNS; m++) gs += sC[m] * wr[m];
      const float val = ((const float*)&x)[j] * gs * sigmoidf_(gs);
      y[j] = val;
      s1 += val;
      s2 += val * val;
    }
#pragma unroll
    for (int o = 32; o > 0; o >>= 1) { s1 += __shfl_xor(s1, o, 64); s2 += __shfl_xor(s2, o, 64); }
    if ((tid & 63) == 0) { rbuf[tid >> 6] = s1; rbuf[4 + (tid >> 6)] = s2; }
    __syncthreads();
    s1 = rbuf[0] + rbuf[1] + rbuf[2] + rbuf[3];
    s2 = rbuf[4] + rbuf[5] + rbuf[6] + rbuf[7];
    const float mean = s1 * (1.f / cD);
    const float var = s2 * (1.f / cD) - mean * mean;
    const float inv = rsqrtf(var + 1e-5f);
    const float4 g = *(const float4*)(lnq_g + d0);
    const float4 b = *(const float4*)(lnq_b + d0);
    float z[4];
    z[0] = (y[0] - mean) * inv * g.x + b.x;
    z[1] = (y[1] - mean) * inv * g.y + b.y;
    z[2] = (y[2] - mean) * inv * g.z + b.z;
    z[3] = (y[3] - mean) * inv * g.w + b.w;
    unsigned short h4[4], l4[4];
#pragma unroll
    for (int j = 0; j < 4; j++) {
      h4[j] = f2bf(z[j]);
      l4[j] = f2bf(z[j] - bf2f(h4[j]));
    }
    *(uint2*)(Yh + (size_t)row * cD + d0) = *(uint2*)h4;
    *(uint2*)(Yl + (size_t)row * cD + d0) = *(uint2*)l4;
  }
}

// ---------------- split-bf16 MFMA GEMM: C[M,N] = A[M,K] @ W[N,K]^T ----------------
// 128x128 tile, BK=32, 512 thr (8 waves, 4x2), double-buffered LDS w/ async prefetch.
// blockIdx.z selects (W,C) pair. MODE 0: fp32 out. MODE 1: scale then hi/lo bf16 split out.
template <int MODE>
__global__ __launch_bounds__(512) void gemm_sp_kernel(
    const unsigned short* __restrict__ Ahi, const unsigned short* __restrict__ Alo,
    const unsigned short* __restrict__ Whi0, const unsigned short* __restrict__ Wlo0,
    const unsigned short* __restrict__ Whi1, const unsigned short* __restrict__ Wlo1,
    float* __restrict__ Cf0, float* __restrict__ Cf1,
    unsigned short* __restrict__ Chi, unsigned short* __restrict__ Clo,
    int M, int N, int K, float scale) {
  __shared__ __align__(16) unsigned short sAh[2][128 * 32];
  __shared__ __align__(16) unsigned short sAl[2][128 * 32];
  __shared__ __align__(16) unsigned short sBh[2][128 * 32];
  __shared__ __align__(16) unsigned short sBl[2][128 * 32];
  const unsigned short* Whi = blockIdx.z ? Whi1 : Whi0;
  const unsigned short* Wlo = blockIdx.z ? Wlo1 : Wlo0;
  float* Cf = blockIdx.z ? Cf1 : Cf0;
  const int tid = threadIdx.x;
  const int wave = tid >> 6, lane = tid & 63;
  const int quad = lane >> 4, l16 = lane & 15;
  const int m0 = blockIdx.y * 128, n0 = blockIdx.x * 128;
  const int wy = wave >> 1, wx = wave & 1;           // wave tile: 32(m) x 64(n)
  const int srow = lane >> 2;                        // row within 16-row staging inst
  const int sg = (lane & 3) ^ ((lane >> 3) & 3);     // permuted global granule

  f32x4 acc[2][4];
#pragma unroll
  for (int i = 0; i < 2; i++)
#pragma unroll
    for (int j = 0; j < 4; j++) acc[i][j] = (f32x4){0.f, 0.f, 0.f, 0.f};

  auto stage = [&](int buf, int k0) {
    const int row = wave * 16 + srow;
    const size_t ga = (size_t)(m0 + row) * K + k0 + sg * 8;
    const size_t gb = (size_t)(n0 + row) * K + k0 + sg * 8;
    async16(Ahi + ga, &sAh[buf][wave * 512]);
    async16(Alo + ga, &sAl[buf][wave * 512]);
    async16(Whi + gb, &sBh[buf][wave * 512]);
    async16(Wlo + gb, &sBl[buf][wave * 512]);
  };

  stage(0, 0);
  __syncthreads();
  const int aswz = (l16 >> 1) & 3;
  int buf = 0;
  for (int k0 = 0; k0 < K; k0 += 32, buf ^= 1) {
    if (k0 + 32 < K) stage(buf ^ 1, k0 + 32);  // drains at iter-end barrier
    short8 bh[4], bl4[4];
#pragma unroll
    for (int t = 0; t < 4; t++) {
      const int br = (wx * 64 + t * 16 + l16) * 32 + ((quad ^ aswz) * 8);
      bh[t] = *(const short8*)&sBh[buf][br];
      bl4[t] = *(const short8*)&sBl[buf][br];
    }
#pragma unroll
    for (int ti = 0; ti < 2; ti++) {
      const int ar = (wy * 32 + ti * 16 + l16) * 32 + ((quad ^ aswz) * 8);
      const short8 ah = *(const short8*)&sAh[buf][ar];
      const short8 al4 = *(const short8*)&sAl[buf][ar];
#pragma unroll
      for (int tj = 0; tj < 4; tj++) {
        acc[ti][tj] = MFMA16(ah, bh[tj], acc[ti][tj]);
        acc[ti][tj] = MFMA16(al4, bh[tj], acc[ti][tj]);
        acc[ti][tj] = MFMA16(ah, bl4[tj], acc[ti][tj]);
      }
    }
    __syncthreads();
  }

#pragma unroll
  for (int ti = 0; ti < 2; ti++)
#pragma unroll
    for (int tj = 0; tj < 4; tj++) {
      const int row = m0 + wy * 32 + ti * 16 + quad * 4;
      const int col = n0 + wx * 64 + tj * 16 + l16;
#pragma unroll
      for (int r = 0; r < 4; r++) {
        const size_t idx = (size_t)(row + r) * N + col;
        if constexpr (MODE == 0) {
          Cf[idx] = acc[ti][tj][r];
        } else {
          const float v = acc[ti][tj][r] * scale;
          const unsigned short hi = f2bf(v);
          Chi[idx] = hi;
          Clo[idx] = f2bf(v - bf2f(hi));
        }
      }
    }
}

// ---------------- fused prep: K gather (row-major) + Vt gather (transposed) ----------------
// grid 3072 x 256: [0,2048) prep_k, [2048,3072) prep_vt.
__global__ __launch_bounds__(256) void prep_kv_kernel(
    const float* __restrict__ Ek, const float* __restrict__ Ev,
    const float* __restrict__ gkv, const int* __restrict__ xidx,
    unsigned short* __restrict__ Khi, unsigned short* __restrict__ Klo,
    unsigned short* __restrict__ Vthi, unsigned short* __restrict__ Vtlo) {
  __shared__ float tile[64][65];
  const int bid = blockIdx.x;
  const int tid = threadIdx.x;
  if (bid < 2048) {  // ---- prep_k ----
    const int t = bid * 256 + tid;
    const int d0 = (t & 127) * 8;
    const int s = (t >> 7) & (cS - 1);
    const int b = t >> 18;
    const int slot = xidx[b * cS + s];
    const float4 e0 = *(const float4*)(Ek + (size_t)slot * cD + d0);
    const float4 e1 = *(const float4*)(Ek + (size_t)slot * cD + d0 + 4);
    const float4 g0 = *(const float4*)(gkv + (size_t)s * cD + d0);
    const float4 g1 = *(const float4*)(gkv + (size_t)s * cD + d0 + 4);
    float v[8] = {e0.x * g0.x, e0.y * g0.y, e0.z * g0.z, e0.w * g0.w,
                  e1.x * g1.x, e1.y * g1.y, e1.z * g1.z, e1.w * g1.w};
    unsigned short h8[8], l8[8];
#pragma unroll
    for (int j = 0; j < 8; j++) {
      h8[j] = f2bf(v[j]);
      l8[j] = f2bf(v[j] - bf2f(h8[j]));
    }
    const size_t off = (size_t)(b * cS + s) * cD + d0;
    *(uint4*)(Khi + off) = *(uint4*)h8;
    *(uint4*)(Klo + off) = *(uint4*)l8;
  } else {  // ---- prep_vt ----
    const int local = bid - 2048;
    const int s0 = (local & 31) * 64;
    const int d0 = ((local >> 5) & 15) * 64;
    const int b = local >> 9;
    const int sl = tid >> 4;
    const int dl = (tid & 15) * 4;
#pragma unroll
    for (int it = 0; it < 4; it++) {
      const int s = s0 + sl + it * 16;
      const int slot = xidx[b * cS + s];
      const float4 e = *(const float4*)(Ev + (size_t)slot * cD + d0 + dl);
      const float4 g = *(const float4*)(gkv + (size_t)s * cD + d0 + dl);
      tile[sl + it * 16][dl + 0] = e.x * g.x;
      tile[sl + it * 16][dl + 1] = e.y * g.y;
      tile[sl + it * 16][dl + 2] = e.z * g.z;
      tile[sl + it * 16][dl + 3] = e.w * g.w;
    }
    __syncthreads();
    const int dr = tid >> 3;
    const int sc = (tid & 7) * 8;
#pragma unroll
    for (int it = 0; it < 2; it++) {
      const int d = d0 + dr + it * 32;
      unsigned short h8[8], l8[8];
#pragma unroll
      for (int j = 0; j < 8; j++) {
        const float v = tile[sc + j][dr + it * 32];
        h8[j] = f2bf(v);
        l8[j] = f2bf(v - bf2f(h8[j]));
      }
      const size_t off = (size_t)(b * cD + d) * cS + s0 + sc;
      *(uint4*)(Vthi + off) = *(uint4*)h8;
      *(uint4*)(Vtlo + off) = *(uint4*)l8;
    }
  }
}

// ---------------- MFMA flash attention v5 ----------------
// grid (L/64, H, B) = 1024 blocks, 256 thr = 4 waves, wave owns 16 l-rows. s-chunk 64.
// Static max (scores bounded ~2.4, exp2 accumulation safe in fp32): no online-softmax
// VALU. V hi-only (lo-term error ~2e-5 post-Wo). Register double-buffered staging.
__global__ __launch_bounds__(256, 3) void attn_mfma_kernel(
    const unsigned short* __restrict__ qhi, const unsigned short* __restrict__ qlo,
    const unsigned short* __restrict__ Khi, const unsigned short* __restrict__ Klo,
    const unsigned short* __restrict__ Vthi,
    unsigned short* __restrict__ AOhi, unsigned short* __restrict__ AOlo) {
  __shared__ __align__(16) unsigned short sKh[64 * 64];
  __shared__ __align__(16) unsigned short sKl[64 * 64];
  __shared__ __align__(16) unsigned short sVh[64 * 64];
  __shared__ __align__(16) unsigned int sPp[4][16][68];  // [wave][l-row][s-col] packed hi|lo

  const int tid = threadIdx.x;
  const int wave = tid >> 6, lane = tid & 63;
  const int quad = lane >> 4, l16 = lane & 15;
  const int lB = blockIdx.x * 64;
  const int h = blockIdx.y, b = blockIdx.z;

  // Q fragments (A-layout); 0.125*log2e folded upstream
  short8 qh[2], ql[2];
  {
    const size_t base = (size_t)(b * cL + lB + wave * 16 + l16) * cD + h * cHD + quad * 8;
    qh[0] = *(const short8*)(qhi + base);
    qh[1] = *(const short8*)(qhi + base + 32);
    ql[0] = *(const short8*)(qlo + base);
    ql[1] = *(const short8*)(qlo + base + 32);
  }

  short8 ones;
#pragma unroll
  for (int i = 0; i < 8; i++) ones[i] = (short)0x3F80;  // bf16 1.0

  f32x4 O[4], dacc;
#pragma unroll
  for (int i = 0; i < 4; i++) O[i] = (f32x4){0.f, 0.f, 0.f, 0.f};
  dacc = (f32x4){0.f, 0.f, 0.f, 0.f};

  const int srow8 = lane >> 3;        // row within 8-row staging slab
  const int sg = (lane & 7) ^ srow8;  // permuted global granule

  const int r0 = (wave * 2 + 0) * 8 + srow8;
  const int r1 = (wave * 2 + 1) * 8 + srow8;
  const size_t kb0 = (size_t)(b * cS + r0) * cD + h * cHD + sg * 8;  // + s*cD
  const size_t kb1 = (size_t)(b * cS + r1) * cD + h * cHD + sg * 8;
  const size_t vb0 = (size_t)(b * cD + h * cHD + r0) * cS + sg * 8;  // + s
  const size_t vb1 = (size_t)(b * cD + h * cHD + r1) * cS + sg * 8;

  // named prefetch registers (NO arrays -> stay in VGPRs; r4's array version spilled)
  uint4 k0h, k0l, v0h, k1h, k1l, v1h;
  k0h = *(const uint4*)(Khi + kb0);
  k0l = *(const uint4*)(Klo + kb0);
  v0h = *(const uint4*)(Vthi + vb0);
  k1h = *(const uint4*)(Khi + kb1);
  k1l = *(const uint4*)(Klo + kb1);
  v1h = *(const uint4*)(Vthi + vb1);

  const int j0 = wave * 2, j1 = wave * 2 + 1;

  for (int s0 = 0; s0 < cS; s0 += 64) {
    __syncthreads();  // all waves done reading LDS from prior chunk
    *(uint4*)&sKh[j0 * 512 + lane * 8] = k0h;
    *(uint4*)&sKl[j0 * 512 + lane * 8] = k0l;
    *(uint4*)&sVh[j0 * 512 + lane * 8] = v0h;
    *(uint4*)&sKh[j1 * 512 + lane * 8] = k1h;
    *(uint4*)&sKl[j1 * 512 + lane * 8] = k1l;
    *(uint4*)&sVh[j1 * 512 + lane * 8] = v1h;
    __syncthreads();

    // unconditional wrapped prefetch of next chunk
    {
      const int sn = (s0 + 64) & (cS - 1);
      const size_t kc = (size_t)sn * cD;
      k0h = *(const uint4*)(Khi + kb0 + kc);
      k0l = *(const uint4*)(Klo + kb0 + kc);
      v0h = *(const uint4*)(Vthi + vb0 + sn);
      k1h = *(const uint4*)(Khi + kb1 + kc);
      k1l = *(const uint4*)(Klo + kb1 + kc);
      v1h = *(const uint4*)(Vthi + vb1 + sn);
    }

    // QK^T, 3-term split (exp2 domain)
    f32x4 sc[4];
#pragma unroll
    for (int st = 0; st < 4; st++) sc[st] = (f32x4){0.f, 0.f, 0.f, 0.f};
#pragma unroll
    for (int st = 0; st < 4; st++) {
      const int srw = st * 16 + l16;
#pragma unroll
      for (int ks = 0; ks < 2; ks++) {
        const int slot = (ks * 4 + quad) ^ (srw & 7);
        const short8 kfh = *(const short8*)&sKh[srw * 64 + slot * 8];
        const short8 kfl = *(const short8*)&sKl[srw * 64 + slot * 8];
        sc[st] = MFMA16(qh[ks], kfh, sc[st]);
        sc[st] = MFMA16(ql[ks], kfh, sc[st]);
        sc[st] = MFMA16(qh[ks], kfl, sc[st]);
      }
    }

    // P = exp2(sc) (static max: scores bounded, no overflow), packed hi/lo -> LDS
#pragma unroll
    for (int st = 0; st < 4; st++)
#pragma unroll
      for (int r = 0; r < 4; r++) {
        const float p = __builtin_amdgcn_exp2f(sc[st][r]);
        sPp[wave][quad * 4 + r][st * 16 + l16] = pack_split(p);
      }

    // P fragments (A-layout), wave-local (same-wave LDS ordering)
    short8 pfh[2], pfl[2];
#pragma unroll
    for (int ss = 0; ss < 2; ss++) {
      const uint4 pa = *(const uint4*)&sPp[wave][l16][ss * 32 + quad * 8];
      const uint4 pb = *(const uint4*)&sPp[wave][l16][ss * 32 + quad * 8 + 4];
      unpack8(pa, pb, pfh[ss], pfl[ss]);
    }
    // PV: (phi+plo) x Vhi
#pragma unroll
    for (int dt = 0; dt < 4; dt++) {
      const int drw = dt * 16 + l16;
#pragma unroll
      for (int ss = 0; ss < 2; ss++) {
        const int slot = (ss * 4 + quad) ^ (drw & 7);
        const short8 vfh = *(const short8*)&sVh[drw * 64 + slot * 8];
        O[dt] = MFMA16(pfh[ss], vfh, O[dt]);
        O[dt] = MFMA16(pfl[ss], vfh, O[dt]);
      }
    }
    // denominator via ones-MFMA
    dacc = MFMA16(pfh[0], ones, dacc);
    dacc = MFMA16(pfl[0], ones, dacc);
    dacc = MFMA16(pfh[1], ones, dacc);
    dacc = MFMA16(pfl[1], ones, dacc);
  }

  // epilogue: row = quad*4+r, col = dt*16+l16; dacc col-replicated
  float inv[4];
#pragma unroll
  for (int r = 0; r < 4; r++) inv[r] = 1.f / dacc[r];
#pragma unroll
  for (int dt = 0; dt < 4; dt++)
#pragma unroll
    for (int r = 0; r < 4; r++) {
      const float v = O[dt][r] * inv[r];
      const unsigned short hi = f2bf(v);
      const size_t l = (size_t)(b * cL + lB + wave * 16 + quad * 4 + r);
      const size_t idx = l * cD + h * cHD + dt * 16 + l16;
      AOhi[idx] = hi;
      AOlo[idx] = f2bf(v - bf2f(hi));
    }
}

}  // namespace

extern "C" void kernel_launch(void* const* d_in, const int* in_sizes, int n_in,
                              void* d_out, int out_size, void* d_ws, size_t ws_size,
                              hipStream_t stream) {
  (void)in_sizes; (void)n_in; (void)out_size; (void)ws_size;
  const float* x_q = (const float*)d_in[0];
  const int* x_idx = (const int*)d_in[1];
  const float* E_slots = (const float*)d_in[2];
  const float* rhos = (const float*)d_in[3];
  const float* C_seq = (const float*)d_in[4];
  const float* Wq = (const float*)d_in[5];
  const float* Wk = (const float*)d_in[6];
  const float* Wv = (const float*)d_in[7];
  const float* Wo = (const float*)d_in[8];
  const float* Wpe = (const float*)d_in[9];
  const float* ln_kv_g = (const float*)d_in[10];
  const float* ln_kv_b = (const float*)d_in[11];
  const float* ln_q_g = (const float*)d_in[12];
  const float* ln_q_b = (const float*)d_in[13];
  float* out = (float*)d_out;

  float* ws = (float*)d_ws;
  unsigned short* memhi = (unsigned short*)(ws + 0);
  unsigned short* memlo = (unsigned short*)(ws + 262144);
  unsigned short* Wkhi = (unsigned short*)(ws + 524288);
  unsigned short* Wklo = (unsigned short*)(ws + 1048576);
  unsigned short* Wvhi = (unsigned short*)(ws + 1572864);
  unsigned short* Wvlo = (unsigned short*)(ws + 2097152);
  float* gkv = ws + 2621440;
  unsigned short* qhi = (unsigned short*)(ws + 0);          // overlay (dead before Q GEMM)
  unsigned short* qlo = (unsigned short*)(ws + 2097152);
  unsigned short* Wqhi = (unsigned short*)(ws + 4718592);
  unsigned short* Wqlo = (unsigned short*)(ws + 5242880);
  unsigned short* Wohi = (unsigned short*)(ws + 5767168);
  unsigned short* Wolo = (unsigned short*)(ws + 6291456);
  float* Ek = ws + 6815744;
  float* Ev = ws + 7340032;
  unsigned short* Yhi = (unsigned short*)(ws + 7864320);
  unsigned short* Ylo = (unsigned short*)(ws + 9961472);
  unsigned short* AOhi = (unsigned short*)(ws + 7864320);   // overlay Y (dead after Q GEMM)
  unsigned short* AOlo = (unsigned short*)(ws + 9961472);
  unsigned short* Khi = (unsigned short*)(ws + 12058624);
  unsigned short* Klo = (unsigned short*)(ws + 14155776);
  unsigned short* Vthi = (unsigned short*)(ws + 16252928);

  constexpr float kQScale = 0.125f * 1.44269504088896340736f;  // 1/sqrt(HD) * log2(e)

  prep_all_kernel<<<8704, 256, 0, stream>>>(
      Wq, Wk, Wv, Wo, Wqhi, Wqlo, Wkhi, Wklo, Wvhi, Wvlo, Wohi, Wolo,
      E_slots, ln_kv_g, ln_kv_b, memhi, memlo, rhos, Wpe, gkv,
      x_q, C_seq, ln_q_g, ln_q_b, Yhi, Ylo);
  gemm_sp_kernel<0><<<dim3(8, 4, 2), 512, 0, stream>>>(
      memhi, memlo, Wkhi, Wklo, Wvhi, Wvlo, Ek, Ev, nullptr, nullptr, cNSLOT, cD, cD, 1.f);
  prep_kv_kernel<<<3072, 256, 0, stream>>>(Ek, Ev, gkv, x_idx, Khi, Klo, Vthi,
                                           (unsigned short*)(ws + 18350080));
  gemm_sp_kernel<1><<<dim3(8, 32, 1), 512, 0, stream>>>(
      Yhi, Ylo, Wqhi, Wqlo, Wqhi, Wqlo, nullptr, nullptr, qhi, qlo, cB * cL, cD, cD, kQScale);
  attn_mfma_kernel<<<dim3(cL / 64, cH, cB), 256, 0, stream>>>(qhi, qlo, Khi, Klo, Vthi,
                                                              AOhi, AOlo);
  gemm_sp_kernel<0><<<dim3(8, 32, 1), 512, 0, stream>>>(
      AOhi, AOlo, Wohi, Wolo, Wohi, Wolo, out, out, nullptr, nullptr, cB * cL, cD, cD, 1.f);
}

// Round 7
// 296.104 us; speedup vs baseline: 1.9073x; 1.1873x over previous
//
#include <hip/hip_runtime.h>
#include <cmath>
#include <cstddef>

namespace {

constexpr int cB = 2, cL = 2048, cS = 2048, cD = 1024, cH = 16, cNS = 8, cNSLOT = 512, cHD = 64;

typedef __attribute__((ext_vector_type(8))) short short8;
typedef __attribute__((ext_vector_type(4))) float f32x4;

#define MFMA16(a, b, c) __builtin_amdgcn_mfma_f32_16x16x32_bf16((a), (b), (c), 0, 0, 0)

__device__ __forceinline__ float sigmoidf_(float x) { return 1.f / (1.f + __expf(-x)); }

__device__ __forceinline__ unsigned short f2bf(float x) {
  union { float f; unsigned u; } c; c.f = x;
  unsigned r = c.u + 0x7FFFu + ((c.u >> 16) & 1u);
  return (unsigned short)(r >> 16);
}
__device__ __forceinline__ float bf2f(unsigned short h) {
  union { unsigned u; float f; } c; c.u = ((unsigned)h) << 16;
  return c.f;
}

// async global->LDS 16B per lane. lds ptr must be wave-uniform base; HW writes base + lane*16.
__device__ __forceinline__ void async16(const void* g, void* l) {
  __builtin_amdgcn_global_load_lds((const __attribute__((address_space(1))) void*)g,
                                   (__attribute__((address_space(3))) void*)l, 16, 0, 0);
}

// ---------------- fused prep: wsplit | ln_slots | gatekv | qgate_ln ----------------
// grid 8704 x 256: [0,2048) weight split, [2048,2560) ln_slots, [2560,4608) gatekv,
// [4608,8704) qgate_ln.
__global__ __launch_bounds__(256) void prep_all_kernel(
    const float* __restrict__ Wq, const float* __restrict__ Wk,
    const float* __restrict__ Wv, const float* __restrict__ Wo,
    unsigned short* __restrict__ Wqh, unsigned short* __restrict__ Wql,
    unsigned short* __restrict__ Wkh, unsigned short* __restrict__ Wkl,
    unsigned short* __restrict__ Wvh, unsigned short* __restrict__ Wvl,
    unsigned short* __restrict__ Woh, unsigned short* __restrict__ Wol,
    const float* __restrict__ E, const float* __restrict__ lnkv_g,
    const float* __restrict__ lnkv_b, unsigned short* __restrict__ mh,
    unsigned short* __restrict__ ml, const float* __restrict__ rhos,
    const float* __restrict__ Wpe, float* __restrict__ gkv,
    const float* __restrict__ xq, const float* __restrict__ Cseq,
    const float* __restrict__ lnq_g, const float* __restrict__ lnq_b,
    unsigned short* __restrict__ Yh, unsigned short* __restrict__ Yl) {
  __shared__ float sC[cNS];
  __shared__ float rbuf[8];
  const int bid = blockIdx.x;
  const int tid = threadIdx.x;

  if (bid < 2048) {  // ---- weight split ----
    const int wid = bid >> 9;
    const size_t off = ((size_t)(bid & 511) * 256 + tid) * 8;
    const float* src = wid == 0 ? Wq : wid == 1 ? Wk : wid == 2 ? Wv : Wo;
    unsigned short* dh = wid == 0 ? Wqh : wid == 1 ? Wkh : wid == 2 ? Wvh : Woh;
    unsigned short* dl = wid == 0 ? Wql : wid == 1 ? Wkl : wid == 2 ? Wvl : Wol;
    const float4 a = *(const float4*)(src + off);
    const float4 b = *(const float4*)(src + off + 4);
    float v[8] = {a.x, a.y, a.z, a.w, b.x, b.y, b.z, b.w};
    unsigned short h8[8], l8[8];
#pragma unroll
    for (int j = 0; j < 8; j++) {
      h8[j] = f2bf(v[j]);
      l8[j] = f2bf(v[j] - bf2f(h8[j]));
    }
    *(uint4*)(dh + off) = *(uint4*)h8;
    *(uint4*)(dl + off) = *(uint4*)l8;
  } else if (bid < 2560) {  // ---- ln_slots ----
    const int row = bid - 2048;
    const int d0 = tid * 4;
    const float4 x = *(const float4*)(E + (size_t)row * cD + d0);
    float s1 = x.x + x.y + x.z + x.w;
    float s2 = x.x * x.x + x.y * x.y + x.z * x.z + x.w * x.w;
#pragma unroll
    for (int o = 32; o > 0; o >>= 1) { s1 += __shfl_xor(s1, o, 64); s2 += __shfl_xor(s2, o, 64); }
    if ((tid & 63) == 0) { rbuf[tid >> 6] = s1; rbuf[4 + (tid >> 6)] = s2; }
    __syncthreads();
    s1 = rbuf[0] + rbuf[1] + rbuf[2] + rbuf[3];
    s2 = rbuf[4] + rbuf[5] + rbuf[6] + rbuf[7];
    const float mean = s1 * (1.f / cD);
    const float var = s2 * (1.f / cD) - mean * mean;
    const float inv = rsqrtf(var + 1e-5f);
    const float4 g = *(const float4*)(lnkv_g + d0);
    const float4 b = *(const float4*)(lnkv_b + d0);
    float y[4];
    y[0] = (x.x - mean) * inv * g.x + b.x;
    y[1] = (x.y - mean) * inv * g.y + b.y;
    y[2] = (x.z - mean) * inv * g.z + b.z;
    y[3] = (x.w - mean) * inv * g.w + b.w;
    unsigned short h4[4], l4[4];
#pragma unroll
    for (int j = 0; j < 4; j++) {
      h4[j] = f2bf(y[j]);
      l4[j] = f2bf(y[j] - bf2f(h4[j]));
    }
    *(uint2*)(mh + (size_t)row * cD + d0) = *(uint2*)h4;
    *(uint2*)(ml + (size_t)row * cD + d0) = *(uint2*)l4;
  } else if (bid < 4608) {  // ---- gatekv ----
    const int s = bid - 2560;
    if (tid < cNS) {
      const float age = (float)(cS - 1 - s);
      sC[tid] = __expf(age * __logf(rhos[tid]));
    }
    __syncthreads();
    const int d0 = tid * 4;
    float4 o4;
#pragma unroll
    for (int j = 0; j < 4; j++) {
      const float* wr = Wpe + (size_t)(d0 + j) * cNS;
      float gs = 0.f;
#pragma unroll
      for (int m = 0; m < cNS; m++) gs += sC[m] * wr[m];
      ((float*)&o4)[j] = gs * sigmoidf_(gs);
    }
    *(float4*)(gkv + (size_t)s * cD + d0) = o4;
  } else {  // ---- qgate_ln ----
    const int row = bid - 4608;
    if (tid < cNS) sC[tid] = Cseq[(size_t)row * cNS + tid];
    __syncthreads();
    const int d0 = tid * 4;
    const float4 x = *(const float4*)(xq + (size_t)row * cD + d0);
    float y[4];
    float s1 = 0.f, s2 = 0.f;
#pragma unroll
    for (int j = 0; j < 4; j++) {
      const float* wr = Wpe + (size_t)(d0 + j) * cNS;
      float gs = 0.f;
#pragma unroll
      for (int m = 0; m < cNS; m++) gs += sC[m] * wr[m];
      const float val = ((const float*)&x)[j] * gs * sigmoidf_(gs);
      y[j] = val;
      s1 += val;
      s2 += val * val;
    }
#pragma unroll
    for (int o = 32; o > 0; o >>= 1) { s1 += __shfl_xor(s1, o, 64); s2 += __shfl_xor(s2, o, 64); }
    if ((tid & 63) == 0) { rbuf[tid >> 6] = s1; rbuf[4 + (tid >> 6)] = s2; }
    __syncthreads();
    s1 = rbuf[0] + rbuf[1] + rbuf[2] + rbuf[3];
    s2 = rbuf[4] + rbuf[5] + rbuf[6] + rbuf[7];
    const float mean = s1 * (1.f / cD);
    const float var = s2 * (1.f / cD) - mean * mean;
    const float inv = rsqrtf(var + 1e-5f);
    const float4 g = *(const float4*)(lnq_g + d0);
    const float4 b = *(const float4*)(lnq_b + d0);
    float z[4];
    z[0] = (y[0] - mean) * inv * g.x + b.x;
    z[1] = (y[1] - mean) * inv * g.y + b.y;
    z[2] = (y[2] - mean) * inv * g.z + b.z;
    z[3] = (y[3] - mean) * inv * g.w + b.w;
    unsigned short h4[4], l4[4];
#pragma unroll
    for (int j = 0; j < 4; j++) {
      h4[j] = f2bf(z[j]);
      l4[j] = f2bf(z[j] - bf2f(h4[j]));
    }
    *(uint2*)(Yh + (size_t)row * cD + d0) = *(uint2*)h4;
    *(uint2*)(Yl + (size_t)row * cD + d0) = *(uint2*)l4;
  }
}

// ---------------- split-bf16 MFMA GEMM v2: C[M,N] = A[M,K] @ W[N,K]^T ----------------
// 128x64 tile, BK=32, 256 thr (4 waves 2x2; wave = 64m x 32n), double-buffered LDS.
// blockIdx.z selects (W,C) pair. MODE 0: fp32 out. MODE 1: scale then bf16-hi out only.
template <int MODE>
__global__ __launch_bounds__(256, 2) void gemm_sp_kernel(
    const unsigned short* __restrict__ Ahi, const unsigned short* __restrict__ Alo,
    const unsigned short* __restrict__ Whi0, const unsigned short* __restrict__ Wlo0,
    const unsigned short* __restrict__ Whi1, const unsigned short* __restrict__ Wlo1,
    float* __restrict__ Cf0, float* __restrict__ Cf1,
    unsigned short* __restrict__ Chi,
    int M, int N, int K, float scale) {
  __shared__ __align__(16) unsigned short sAh[2][128 * 32];
  __shared__ __align__(16) unsigned short sAl[2][128 * 32];
  __shared__ __align__(16) unsigned short sBh[2][64 * 32];
  __shared__ __align__(16) unsigned short sBl[2][64 * 32];
  const unsigned short* Whi = blockIdx.z ? Whi1 : Whi0;
  const unsigned short* Wlo = blockIdx.z ? Wlo1 : Wlo0;
  float* Cf = blockIdx.z ? Cf1 : Cf0;
  const int tid = threadIdx.x;
  const int wave = tid >> 6, lane = tid & 63;
  const int quad = lane >> 4, l16 = lane & 15;
  const int m0 = blockIdx.y * 128, n0 = blockIdx.x * 64;
  const int wy = wave >> 1, wx = wave & 1;        // wave tile: 64(m) x 32(n)
  const int sg = (lane & 3) ^ ((lane >> 3) & 3);  // permuted global granule
  const int srow = lane >> 2;                     // row within wave's 16-row staging slab

  f32x4 acc[4][2];
#pragma unroll
  for (int i = 0; i < 4; i++)
#pragma unroll
    for (int j = 0; j < 2; j++) acc[i][j] = (f32x4){0.f, 0.f, 0.f, 0.f};

  auto stage = [&](int buf, int k0) {
#pragma unroll
    for (int c = 0; c < 2; c++) {
      const int row = c * 64 + wave * 16 + srow;
      const size_t ga = (size_t)(m0 + row) * K + k0 + sg * 8;
      async16(Ahi + ga, &sAh[buf][(c * 64 + wave * 16) * 32]);
      async16(Alo + ga, &sAl[buf][(c * 64 + wave * 16) * 32]);
    }
    const int rowb = wave * 16 + srow;
    const size_t gb = (size_t)(n0 + rowb) * K + k0 + sg * 8;
    async16(Whi + gb, &sBh[buf][wave * 16 * 32]);
    async16(Wlo + gb, &sBl[buf][wave * 16 * 32]);
  };

  stage(0, 0);
  __syncthreads();
  const int aswz = (l16 >> 1) & 3;
  int buf = 0;
  for (int k0 = 0; k0 < K; k0 += 32, buf ^= 1) {
    if (k0 + 32 < K) stage(buf ^ 1, k0 + 32);  // drains at iter-end barrier
    short8 bh[2], bl2[2];
#pragma unroll
    for (int tj = 0; tj < 2; tj++) {
      const int br = (wx * 32 + tj * 16 + l16) * 32 + ((quad ^ aswz) * 8);
      bh[tj] = *(const short8*)&sBh[buf][br];
      bl2[tj] = *(const short8*)&sBl[buf][br];
    }
#pragma unroll
    for (int ti = 0; ti < 4; ti++) {
      const int ar = (wy * 64 + ti * 16 + l16) * 32 + ((quad ^ aswz) * 8);
      const short8 ah = *(const short8*)&sAh[buf][ar];
      const short8 al2 = *(const short8*)&sAl[buf][ar];
#pragma unroll
      for (int tj = 0; tj < 2; tj++) {
        acc[ti][tj] = MFMA16(ah, bh[tj], acc[ti][tj]);
        acc[ti][tj] = MFMA16(al2, bh[tj], acc[ti][tj]);
        acc[ti][tj] = MFMA16(ah, bl2[tj], acc[ti][tj]);
      }
    }
    __syncthreads();
  }

#pragma unroll
  for (int ti = 0; ti < 4; ti++)
#pragma unroll
    for (int tj = 0; tj < 2; tj++) {
      const int row = m0 + wy * 64 + ti * 16 + quad * 4;
      const int col = n0 + wx * 32 + tj * 16 + l16;
#pragma unroll
      for (int r = 0; r < 4; r++) {
        const size_t idx = (size_t)(row + r) * N + col;
        if constexpr (MODE == 0) {
          Cf[idx] = acc[ti][tj][r];
        } else {
          Chi[idx] = f2bf(acc[ti][tj][r] * scale);
        }
      }
    }
}

// ---------------- fused prep: K gather (row-major, hi) + Vt gather (transposed, hi) ----------------
// grid 3072 x 256: [0,2048) prep_k, [2048,3072) prep_vt.
__global__ __launch_bounds__(256) void prep_kv_kernel(
    const float* __restrict__ Ek, const float* __restrict__ Ev,
    const float* __restrict__ gkv, const int* __restrict__ xidx,
    unsigned short* __restrict__ Khi, unsigned short* __restrict__ Vthi) {
  __shared__ float tile[64][65];
  const int bid = blockIdx.x;
  const int tid = threadIdx.x;
  if (bid < 2048) {  // ---- prep_k ----
    const int t = bid * 256 + tid;
    const int d0 = (t & 127) * 8;
    const int s = (t >> 7) & (cS - 1);
    const int b = t >> 18;
    const int slot = xidx[b * cS + s];
    const float4 e0 = *(const float4*)(Ek + (size_t)slot * cD + d0);
    const float4 e1 = *(const float4*)(Ek + (size_t)slot * cD + d0 + 4);
    const float4 g0 = *(const float4*)(gkv + (size_t)s * cD + d0);
    const float4 g1 = *(const float4*)(gkv + (size_t)s * cD + d0 + 4);
    float v[8] = {e0.x * g0.x, e0.y * g0.y, e0.z * g0.z, e0.w * g0.w,
                  e1.x * g1.x, e1.y * g1.y, e1.z * g1.z, e1.w * g1.w};
    unsigned short h8[8];
#pragma unroll
    for (int j = 0; j < 8; j++) h8[j] = f2bf(v[j]);
    *(uint4*)(Khi + (size_t)(b * cS + s) * cD + d0) = *(uint4*)h8;
  } else {  // ---- prep_vt ----
    const int local = bid - 2048;
    const int s0 = (local & 31) * 64;
    const int d0 = ((local >> 5) & 15) * 64;
    const int b = local >> 9;
    const int sl = tid >> 4;
    const int dl = (tid & 15) * 4;
#pragma unroll
    for (int it = 0; it < 4; it++) {
      const int s = s0 + sl + it * 16;
      const int slot = xidx[b * cS + s];
      const float4 e = *(const float4*)(Ev + (size_t)slot * cD + d0 + dl);
      const float4 g = *(const float4*)(gkv + (size_t)s * cD + d0 + dl);
      tile[sl + it * 16][dl + 0] = e.x * g.x;
      tile[sl + it * 16][dl + 1] = e.y * g.y;
      tile[sl + it * 16][dl + 2] = e.z * g.z;
      tile[sl + it * 16][dl + 3] = e.w * g.w;
    }
    __syncthreads();
    const int dr = tid >> 3;
    const int sc = (tid & 7) * 8;
#pragma unroll
    for (int it = 0; it < 2; it++) {
      const int d = d0 + dr + it * 32;
      unsigned short h8[8];
#pragma unroll
      for (int j = 0; j < 8; j++) h8[j] = f2bf(tile[sc + j][dr + it * 32]);
      *(uint4*)(Vthi + (size_t)(b * cD + d) * cS + s0 + sc) = *(uint4*)h8;
    }
  }
}

// ---------------- MFMA flash attention v6: pure-bf16 internals ----------------
// grid (L/64, H, B) = 1024 blocks, 256 thr = 4 waves, wave owns 16 l-rows. s-chunk 64.
// Softmax averaging suppresses per-(l,s) rounding by ~0.025x, and O = sum(Pv)/sum(P)
// cancels P errors in the ratio -> single-bf16 Q,K,P,V inside attention (~1e-5 output
// error). Projections keep 3-term splits. Static max; den via ones-MFMA.
__global__ __launch_bounds__(256, 4) void attn_mfma_kernel(
    const unsigned short* __restrict__ qhi,
    const unsigned short* __restrict__ Khi,
    const unsigned short* __restrict__ Vthi,
    unsigned short* __restrict__ AOhi, unsigned short* __restrict__ AOlo) {
  __shared__ __align__(16) unsigned short sKh[64 * 64];
  __shared__ __align__(16) unsigned short sVh[64 * 64];
  __shared__ __align__(16) unsigned short sP[4][16][72];  // [wave][l-row][s-col]

  const int tid = threadIdx.x;
  const int wave = tid >> 6, lane = tid & 63;
  const int quad = lane >> 4, l16 = lane & 15;
  const int lB = blockIdx.x * 64;
  const int h = blockIdx.y, b = blockIdx.z;

  // Q fragments (A-layout); 0.125*log2e folded upstream
  short8 qh[2];
  {
    const size_t base = (size_t)(b * cL + lB + wave * 16 + l16) * cD + h * cHD + quad * 8;
    qh[0] = *(const short8*)(qhi + base);
    qh[1] = *(const short8*)(qhi + base + 32);
  }

  short8 ones;
#pragma unroll
  for (int i = 0; i < 8; i++) ones[i] = (short)0x3F80;  // bf16 1.0

  f32x4 O[4], dacc;
#pragma unroll
  for (int i = 0; i < 4; i++) O[i] = (f32x4){0.f, 0.f, 0.f, 0.f};
  dacc = (f32x4){0.f, 0.f, 0.f, 0.f};

  const int srow8 = lane >> 3;        // row within 8-row staging slab
  const int sg = (lane & 7) ^ srow8;  // permuted global granule

  const int r0 = (wave * 2 + 0) * 8 + srow8;
  const int r1 = (wave * 2 + 1) * 8 + srow8;
  const size_t kb0 = (size_t)(b * cS + r0) * cD + h * cHD + sg * 8;  // + s*cD
  const size_t kb1 = (size_t)(b * cS + r1) * cD + h * cHD + sg * 8;
  const size_t vb0 = (size_t)(b * cD + h * cHD + r0) * cS + sg * 8;  // + s
  const size_t vb1 = (size_t)(b * cD + h * cHD + r1) * cS + sg * 8;

  // named prefetch registers (NO arrays -> stay in VGPRs; r4's array version spilled)
  uint4 k0h, v0h, k1h, v1h;
  k0h = *(const uint4*)(Khi + kb0);
  v0h = *(const uint4*)(Vthi + vb0);
  k1h = *(const uint4*)(Khi + kb1);
  v1h = *(const uint4*)(Vthi + vb1);

  const int j0 = wave * 2, j1 = wave * 2 + 1;

  for (int s0 = 0; s0 < cS; s0 += 64) {
    __syncthreads();  // all waves done reading LDS from prior chunk
    *(uint4*)&sKh[j0 * 512 + lane * 8] = k0h;
    *(uint4*)&sVh[j0 * 512 + lane * 8] = v0h;
    *(uint4*)&sKh[j1 * 512 + lane * 8] = k1h;
    *(uint4*)&sVh[j1 * 512 + lane * 8] = v1h;
    __syncthreads();

    // unconditional wrapped prefetch of next chunk
    {
      const int sn = (s0 + 64) & (cS - 1);
      const size_t kc = (size_t)sn * cD;
      k0h = *(const uint4*)(Khi + kb0 + kc);
      v0h = *(const uint4*)(Vthi + vb0 + sn);
      k1h = *(const uint4*)(Khi + kb1 + kc);
      v1h = *(const uint4*)(Vthi + vb1 + sn);
    }

    // QK^T single-bf16 (exp2 domain)
    f32x4 sc[4];
#pragma unroll
    for (int st = 0; st < 4; st++) sc[st] = (f32x4){0.f, 0.f, 0.f, 0.f};
#pragma unroll
    for (int st = 0; st < 4; st++) {
      const int srw = st * 16 + l16;
#pragma unroll
      for (int ks = 0; ks < 2; ks++) {
        const int slot = (ks * 4 + quad) ^ (srw & 7);
        const short8 kfh = *(const short8*)&sKh[srw * 64 + slot * 8];
        sc[st] = MFMA16(qh[ks], kfh, sc[st]);
      }
    }

    // P = exp2(sc) (static max: scores bounded ~3, no overflow), bf16 -> LDS
#pragma unroll
    for (int st = 0; st < 4; st++)
#pragma unroll
      for (int r = 0; r < 4; r++)
        sP[wave][quad * 4 + r][st * 16 + l16] = f2bf(__builtin_amdgcn_exp2f(sc[st][r]));

    // P fragments (A-layout), wave-local (compiler inserts lgkmcnt wait)
    short8 pfh[2];
    pfh[0] = *(const short8*)&sP[wave][l16][quad * 8];
    pfh[1] = *(const short8*)&sP[wave][l16][32 + quad * 8];

    // PV single-bf16
#pragma unroll
    for (int dt = 0; dt < 4; dt++) {
      const int drw = dt * 16 + l16;
#pragma unroll
      for (int ss = 0; ss < 2; ss++) {
        const int slot = (ss * 4 + quad) ^ (drw & 7);
        const short8 vfh = *(const short8*)&sVh[drw * 64 + slot * 8];
        O[dt] = MFMA16(pfh[ss], vfh, O[dt]);
      }
    }
    // denominator via ones-MFMA (consistent with hi-only P used in PV)
    dacc = MFMA16(pfh[0], ones, dacc);
    dacc = MFMA16(pfh[1], ones, dacc);
  }

  // epilogue: row = quad*4+r, col = dt*16+l16; dacc col-replicated. AO split hi/lo
  // (O-projection needs the split).
  float inv[4];
#pragma unroll
  for (int r = 0; r < 4; r++) inv[r] = 1.f / dacc[r];
#pragma unroll
  for (int dt = 0; dt < 4; dt++)
#pragma unroll
    for (int r = 0; r < 4; r++) {
      const float v = O[dt][r] * inv[r];
      const unsigned short hi = f2bf(v);
      const size_t l = (size_t)(b * cL + lB + wave * 16 + quad * 4 + r);
      const size_t idx = l * cD + h * cHD + dt * 16 + l16;
      AOhi[idx] = hi;
      AOlo[idx] = f2bf(v - bf2f(hi));
    }
}

}  // namespace

extern "C" void kernel_launch(void* const* d_in, const int* in_sizes, int n_in,
                              void* d_out, int out_size, void* d_ws, size_t ws_size,
                              hipStream_t stream) {
  (void)in_sizes; (void)n_in; (void)out_size; (void)ws_size;
  const float* x_q = (const float*)d_in[0];
  const int* x_idx = (const int*)d_in[1];
  const float* E_slots = (const float*)d_in[2];
  const float* rhos = (const float*)d_in[3];
  const float* C_seq = (const float*)d_in[4];
  const float* Wq = (const float*)d_in[5];
  const float* Wk = (const float*)d_in[6];
  const float* Wv = (const float*)d_in[7];
  const float* Wo = (const float*)d_in[8];
  const float* Wpe = (const float*)d_in[9];
  const float* ln_kv_g = (const float*)d_in[10];
  const float* ln_kv_b = (const float*)d_in[11];
  const float* ln_q_g = (const float*)d_in[12];
  const float* ln_q_b = (const float*)d_in[13];
  float* out = (float*)d_out;

  float* ws = (float*)d_ws;
  unsigned short* memhi = (unsigned short*)(ws + 0);
  unsigned short* memlo = (unsigned short*)(ws + 262144);
  unsigned short* Wkhi = (unsigned short*)(ws + 524288);
  unsigned short* Wklo = (unsigned short*)(ws + 1048576);
  unsigned short* Wvhi = (unsigned short*)(ws + 1572864);
  unsigned short* Wvlo = (unsigned short*)(ws + 2097152);
  float* gkv = ws + 2621440;
  unsigned short* qhi = (unsigned short*)(ws + 0);          // overlay (dead before Q GEMM)
  unsigned short* Wqhi = (unsigned short*)(ws + 4718592);
  unsigned short* Wqlo = (unsigned short*)(ws + 5242880);
  unsigned short* Wohi = (unsigned short*)(ws + 5767168);
  unsigned short* Wolo = (unsigned short*)(ws + 6291456);
  float* Ek = ws + 6815744;
  float* Ev = ws + 7340032;
  unsigned short* Yhi = (unsigned short*)(ws + 7864320);
  unsigned short* Ylo = (unsigned short*)(ws + 9961472);
  unsigned short* AOhi = (unsigned short*)(ws + 7864320);   // overlay Y (dead after Q GEMM)
  unsigned short* AOlo = (unsigned short*)(ws + 9961472);
  unsigned short* Khi = (unsigned short*)(ws + 12058624);
  unsigned short* Vthi = (unsigned short*)(ws + 16252928);

  constexpr float kQScale = 0.125f * 1.44269504088896340736f;  // 1/sqrt(HD) * log2(e)

  prep_all_kernel<<<8704, 256, 0, stream>>>(
      Wq, Wk, Wv, Wo, Wqhi, Wqlo, Wkhi, Wklo, Wvhi, Wvlo, Wohi, Wolo,
      E_slots, ln_kv_g, ln_kv_b, memhi, memlo, rhos, Wpe, gkv,
      x_q, C_seq, ln_q_g, ln_q_b, Yhi, Ylo);
  gemm_sp_kernel<0><<<dim3(16, 4, 2), 256, 0, stream>>>(
      memhi, memlo, Wkhi, Wklo, Wvhi, Wvlo, Ek, Ev, nullptr, cNSLOT, cD, cD, 1.f);
  prep_kv_kernel<<<3072, 256, 0, stream>>>(Ek, Ev, gkv, x_idx, Khi, Vthi);
  gemm_sp_kernel<1><<<dim3(16, 32, 1), 256, 0, stream>>>(
      Yhi, Ylo, Wqhi, Wqlo, Wqhi, Wqlo, nullptr, nullptr, qhi, cB * cL, cD, cD, kQScale);
  attn_mfma_kernel<<<dim3(cL / 64, cH, cB), 256, 0, stream>>>(qhi, Khi, Vthi, AOhi, AOlo);
  gemm_sp_kernel<0><<<dim3(16, 32, 1), 256, 0, stream>>>(
      AOhi, AOlo, Wohi, Wolo, Wohi, Wolo, out, out, nullptr, cB * cL, cD, cD, 1.f);
}

// Round 8
// 267.354 us; speedup vs baseline: 2.1124x; 1.1075x over previous
//
#include <hip/hip_runtime.h>
#include <cmath>
#include <cstddef>

namespace {

constexpr int cB = 2, cL = 2048, cS = 2048, cD = 1024, cH = 16, cNS = 8, cNSLOT = 512, cHD = 64;

typedef __attribute__((ext_vector_type(8))) short short8;
typedef __attribute__((ext_vector_type(4))) float f32x4;

#define MFMA16(a, b, c) __builtin_amdgcn_mfma_f32_16x16x32_bf16((a), (b), (c), 0, 0, 0)

__device__ __forceinline__ float sigmoidf_(float x) { return 1.f / (1.f + __expf(-x)); }

__device__ __forceinline__ unsigned short f2bf(float x) {
  union { float f; unsigned u; } c; c.f = x;
  unsigned r = c.u + 0x7FFFu + ((c.u >> 16) & 1u);
  return (unsigned short)(r >> 16);
}
__device__ __forceinline__ float bf2f(unsigned short h) {
  union { unsigned u; float f; } c; c.u = ((unsigned)h) << 16;
  return c.f;
}

// async global->LDS 16B per lane. lds ptr must be wave-uniform base; HW writes base + lane*16.
__device__ __forceinline__ void async16(const void* g, void* l) {
  __builtin_amdgcn_global_load_lds((const __attribute__((address_space(1))) void*)g,
                                   (__attribute__((address_space(3))) void*)l, 16, 0, 0);
}

// ---------------- fused prep: wsplit | ln_slots | gatekv | qgate_ln ----------------
// grid 8704 x 256: [0,2048) weight split, [2048,2560) ln_slots, [2560,4608) gatekv,
// [4608,8704) qgate_ln.  Activations (mem, Y) emitted hi-only: downstream GEMMs are
// 2-term (act-hi x weight hi/lo), whose error is below the bf16 rounding already
// applied to their outputs.
__global__ __launch_bounds__(256) void prep_all_kernel(
    const float* __restrict__ Wq, const float* __restrict__ Wk,
    const float* __restrict__ Wv, const float* __restrict__ Wo,
    unsigned short* __restrict__ Wqh, unsigned short* __restrict__ Wql,
    unsigned short* __restrict__ Wkh, unsigned short* __restrict__ Wkl,
    unsigned short* __restrict__ Wvh, unsigned short* __restrict__ Wvl,
    unsigned short* __restrict__ Woh, unsigned short* __restrict__ Wol,
    const float* __restrict__ E, const float* __restrict__ lnkv_g,
    const float* __restrict__ lnkv_b, unsigned short* __restrict__ mh,
    const float* __restrict__ rhos,
    const float* __restrict__ Wpe, float* __restrict__ gkv,
    const float* __restrict__ xq, const float* __restrict__ Cseq,
    const float* __restrict__ lnq_g, const float* __restrict__ lnq_b,
    unsigned short* __restrict__ Yh) {
  __shared__ float sC[cNS];
  __shared__ float rbuf[8];
  const int bid = blockIdx.x;
  const int tid = threadIdx.x;

  if (bid < 2048) {  // ---- weight split (weights keep hi+lo: they are the B operand) ----
    const int wid = bid >> 9;
    const size_t off = ((size_t)(bid & 511) * 256 + tid) * 8;
    const float* src = wid == 0 ? Wq : wid == 1 ? Wk : wid == 2 ? Wv : Wo;
    unsigned short* dh = wid == 0 ? Wqh : wid == 1 ? Wkh : wid == 2 ? Wvh : Woh;
    unsigned short* dl = wid == 0 ? Wql : wid == 1 ? Wkl : wid == 2 ? Wvl : Wol;
    const float4 a = *(const float4*)(src + off);
    const float4 b = *(const float4*)(src + off + 4);
    float v[8] = {a.x, a.y, a.z, a.w, b.x, b.y, b.z, b.w};
    unsigned short h8[8], l8[8];
#pragma unroll
    for (int j = 0; j < 8; j++) {
      h8[j] = f2bf(v[j]);
      l8[j] = f2bf(v[j] - bf2f(h8[j]));
    }
    *(uint4*)(dh + off) = *(uint4*)h8;
    *(uint4*)(dl + off) = *(uint4*)l8;
  } else if (bid < 2560) {  // ---- ln_slots -> bf16 hi ----
    const int row = bid - 2048;
    const int d0 = tid * 4;
    const float4 x = *(const float4*)(E + (size_t)row * cD + d0);
    float s1 = x.x + x.y + x.z + x.w;
    float s2 = x.x * x.x + x.y * x.y + x.z * x.z + x.w * x.w;
#pragma unroll
    for (int o = 32; o > 0; o >>= 1) { s1 += __shfl_xor(s1, o, 64); s2 += __shfl_xor(s2, o, 64); }
    if ((tid & 63) == 0) { rbuf[tid >> 6] = s1; rbuf[4 + (tid >> 6)] = s2; }
    __syncthreads();
    s1 = rbuf[0] + rbuf[1] + rbuf[2] + rbuf[3];
    s2 = rbuf[4] + rbuf[5] + rbuf[6] + rbuf[7];
    const float mean = s1 * (1.f / cD);
    const float var = s2 * (1.f / cD) - mean * mean;
    const float inv = rsqrtf(var + 1e-5f);
    const float4 g = *(const float4*)(lnkv_g + d0);
    const float4 b = *(const float4*)(lnkv_b + d0);
    unsigned short h4[4];
    h4[0] = f2bf((x.x - mean) * inv * g.x + b.x);
    h4[1] = f2bf((x.y - mean) * inv * g.y + b.y);
    h4[2] = f2bf((x.z - mean) * inv * g.z + b.z);
    h4[3] = f2bf((x.w - mean) * inv * g.w + b.w);
    *(uint2*)(mh + (size_t)row * cD + d0) = *(uint2*)h4;
  } else if (bid < 4608) {  // ---- gatekv ----
    const int s = bid - 2560;
    if (tid < cNS) {
      const float age = (float)(cS - 1 - s);
      sC[tid] = __expf(age * __logf(rhos[tid]));
    }
    __syncthreads();
    const int d0 = tid * 4;
    float4 o4;
#pragma unroll
    for (int j = 0; j < 4; j++) {
      const float* wr = Wpe + (size_t)(d0 + j) * cNS;
      float gs = 0.f;
#pragma unroll
      for (int m = 0; m < cNS; m++) gs += sC[m] * wr[m];
      ((float*)&o4)[j] = gs * sigmoidf_(gs);
    }
    *(float4*)(gkv + (size_t)s * cD + d0) = o4;
  } else {  // ---- qgate_ln -> bf16 hi ----
    const int row = bid - 4608;
    if (tid < cNS) sC[tid] = Cseq[(size_t)row * cNS + tid];
    __syncthreads();
    const int d0 = tid * 4;
    const float4 x = *(const float4*)(xq + (size_t)row * cD + d0);
    float y[4];
    float s1 = 0.f, s2 = 0.f;
#pragma unroll
    for (int j = 0; j < 4; j++) {
      const float* wr = Wpe + (size_t)(d0 + j) * cNS;
      float gs = 0.f;
#pragma unroll
      for (int m = 0; m < cNS; m++) gs += sC[m] * wr[m];
      const float val = ((const float*)&x)[j] * gs * sigmoidf_(gs);
      y[j] = val;
      s1 += val;
      s2 += val * val;
    }
#pragma unroll
    for (int o = 32; o > 0; o >>= 1) { s1 += __shfl_xor(s1, o, 64); s2 += __shfl_xor(s2, o, 64); }
    if ((tid & 63) == 0) { rbuf[tid >> 6] = s1; rbuf[4 + (tid >> 6)] = s2; }
    __syncthreads();
    s1 = rbuf[0] + rbuf[1] + rbuf[2] + rbuf[3];
    s2 = rbuf[4] + rbuf[5] + rbuf[6] + rbuf[7];
    const float mean = s1 * (1.f / cD);
    const float var = s2 * (1.f / cD) - mean * mean;
    const float inv = rsqrtf(var + 1e-5f);
    const float4 g = *(const float4*)(lnq_g + d0);
    const float4 b = *(const float4*)(lnq_b + d0);
    unsigned short h4[4];
    h4[0] = f2bf((y[0] - mean) * inv * g.x + b.x);
    h4[1] = f2bf((y[1] - mean) * inv * g.y + b.y);
    h4[2] = f2bf((y[2] - mean) * inv * g.z + b.z);
    h4[3] = f2bf((y[3] - mean) * inv * g.w + b.w);
    *(uint2*)(Yh + (size_t)row * cD + d0) = *(uint2*)h4;
  }
}

// ---------------- 2-term split GEMM: C[M,N] = A_hi[M,K] @ (W_hi + W_lo)[N,K]^T ----------------
// 128x64 tile, BK=32, 256 thr (4 waves 2x2; wave = 64m x 32n), double-buffered LDS.
// blockIdx.z selects (W,C) pair. MODE 0: fp32 out. MODE 1: scale then bf16-hi out.
template <int MODE>
__global__ __launch_bounds__(256, 2) void gemm2_kernel(
    const unsigned short* __restrict__ Ahi,
    const unsigned short* __restrict__ Whi0, const unsigned short* __restrict__ Wlo0,
    const unsigned short* __restrict__ Whi1, const unsigned short* __restrict__ Wlo1,
    float* __restrict__ Cf0, float* __restrict__ Cf1,
    unsigned short* __restrict__ Chi,
    int M, int N, int K, float scale) {
  __shared__ __align__(16) unsigned short sA[2][128 * 32];
  __shared__ __align__(16) unsigned short sBh[2][64 * 32];
  __shared__ __align__(16) unsigned short sBl[2][64 * 32];
  const unsigned short* Whi = blockIdx.z ? Whi1 : Whi0;
  const unsigned short* Wlo = blockIdx.z ? Wlo1 : Wlo0;
  float* Cf = blockIdx.z ? Cf1 : Cf0;
  const int tid = threadIdx.x;
  const int wave = tid >> 6, lane = tid & 63;
  const int quad = lane >> 4, l16 = lane & 15;
  const int m0 = blockIdx.y * 128, n0 = blockIdx.x * 64;
  const int wy = wave >> 1, wx = wave & 1;        // wave tile: 64(m) x 32(n)
  const int sg = (lane & 3) ^ ((lane >> 3) & 3);  // permuted global granule
  const int srow = lane >> 2;                     // row within a 16-row staging slab

  f32x4 acc[4][2];
#pragma unroll
  for (int i = 0; i < 4; i++)
#pragma unroll
    for (int j = 0; j < 2; j++) acc[i][j] = (f32x4){0.f, 0.f, 0.f, 0.f};

  auto stage = [&](int buf, int k0) {
#pragma unroll
    for (int c = 0; c < 2; c++) {
      const int row = c * 64 + wave * 16 + srow;
      const size_t ga = (size_t)(m0 + row) * K + k0 + sg * 8;
      async16(Ahi + ga, &sA[buf][(c * 64 + wave * 16) * 32]);
    }
    const int rowb = wave * 16 + srow;
    const size_t gb = (size_t)(n0 + rowb) * K + k0 + sg * 8;
    async16(Whi + gb, &sBh[buf][wave * 16 * 32]);
    async16(Wlo + gb, &sBl[buf][wave * 16 * 32]);
  };

  stage(0, 0);
  __syncthreads();
  const int aswz = (l16 >> 1) & 3;
  int buf = 0;
  for (int k0 = 0; k0 < K; k0 += 32, buf ^= 1) {
    if (k0 + 32 < K) stage(buf ^ 1, k0 + 32);  // drains at iter-end barrier
    short8 bh[2], bl2[2];
#pragma unroll
    for (int tj = 0; tj < 2; tj++) {
      const int br = (wx * 32 + tj * 16 + l16) * 32 + ((quad ^ aswz) * 8);
      bh[tj] = *(const short8*)&sBh[buf][br];
      bl2[tj] = *(const short8*)&sBl[buf][br];
    }
#pragma unroll
    for (int ti = 0; ti < 4; ti++) {
      const int ar = (wy * 64 + ti * 16 + l16) * 32 + ((quad ^ aswz) * 8);
      const short8 ah = *(const short8*)&sA[buf][ar];
#pragma unroll
      for (int tj = 0; tj < 2; tj++) {
        acc[ti][tj] = MFMA16(ah, bh[tj], acc[ti][tj]);
        acc[ti][tj] = MFMA16(ah, bl2[tj], acc[ti][tj]);
      }
    }
    __syncthreads();
  }

#pragma unroll
  for (int ti = 0; ti < 4; ti++)
#pragma unroll
    for (int tj = 0; tj < 2; tj++) {
      const int row = m0 + wy * 64 + ti * 16 + quad * 4;
      const int col = n0 + wx * 32 + tj * 16 + l16;
#pragma unroll
      for (int r = 0; r < 4; r++) {
        const size_t idx = (size_t)(row + r) * N + col;
        if constexpr (MODE == 0) {
          Cf[idx] = acc[ti][tj][r];
        } else {
          Chi[idx] = f2bf(acc[ti][tj][r] * scale);
        }
      }
    }
}

// ---------------- fused prep: K gather (row-major, hi) + Vt gather (transposed, hi) ----------------
// grid 3072 x 256: [0,2048) prep_k, [2048,3072) prep_vt.
__global__ __launch_bounds__(256) void prep_kv_kernel(
    const float* __restrict__ Ek, const float* __restrict__ Ev,
    const float* __restrict__ gkv, const int* __restrict__ xidx,
    unsigned short* __restrict__ Khi, unsigned short* __restrict__ Vthi) {
  __shared__ float tile[64][65];
  const int bid = blockIdx.x;
  const int tid = threadIdx.x;
  if (bid < 2048) {  // ---- prep_k ----
    const int t = bid * 256 + tid;
    const int d0 = (t & 127) * 8;
    const int s = (t >> 7) & (cS - 1);
    const int b = t >> 18;
    const int slot = xidx[b * cS + s];
    const float4 e0 = *(const float4*)(Ek + (size_t)slot * cD + d0);
    const float4 e1 = *(const float4*)(Ek + (size_t)slot * cD + d0 + 4);
    const float4 g0 = *(const float4*)(gkv + (size_t)s * cD + d0);
    const float4 g1 = *(const float4*)(gkv + (size_t)s * cD + d0 + 4);
    float v[8] = {e0.x * g0.x, e0.y * g0.y, e0.z * g0.z, e0.w * g0.w,
                  e1.x * g1.x, e1.y * g1.y, e1.z * g1.z, e1.w * g1.w};
    unsigned short h8[8];
#pragma unroll
    for (int j = 0; j < 8; j++) h8[j] = f2bf(v[j]);
    *(uint4*)(Khi + (size_t)(b * cS + s) * cD + d0) = *(uint4*)h8;
  } else {  // ---- prep_vt ----
    const int local = bid - 2048;
    const int s0 = (local & 31) * 64;
    const int d0 = ((local >> 5) & 15) * 64;
    const int b = local >> 9;
    const int sl = tid >> 4;
    const int dl = (tid & 15) * 4;
#pragma unroll
    for (int it = 0; it < 4; it++) {
      const int s = s0 + sl + it * 16;
      const int slot = xidx[b * cS + s];
      const float4 e = *(const float4*)(Ev + (size_t)slot * cD + d0 + dl);
      const float4 g = *(const float4*)(gkv + (size_t)s * cD + d0 + dl);
      tile[sl + it * 16][dl + 0] = e.x * g.x;
      tile[sl + it * 16][dl + 1] = e.y * g.y;
      tile[sl + it * 16][dl + 2] = e.z * g.z;
      tile[sl + it * 16][dl + 3] = e.w * g.w;
    }
    __syncthreads();
    const int dr = tid >> 3;
    const int sc = (tid & 7) * 8;
#pragma unroll
    for (int it = 0; it < 2; it++) {
      const int d = d0 + dr + it * 32;
      unsigned short h8[8];
#pragma unroll
      for (int j = 0; j < 8; j++) h8[j] = f2bf(tile[sc + j][dr + it * 32]);
      *(uint4*)(Vthi + (size_t)(b * cD + d) * cS + s0 + sc) = *(uint4*)h8;
    }
  }
}

// ---------------- MFMA flash attention v7: 32 l-rows/wave (LDS-read amortization) ----------------
// grid (L/128, H, B) = 512 blocks, 256 thr = 4 waves, wave owns 32 l-rows (2 bands).
// s-chunk 64. Attention is LDS-pipe-bound: each K/V fragment read now feeds 2 MFMAs.
// Pure-bf16 internals; static max; den via ones-MFMA; AO written hi-only (2-term O-GEMM).
__global__ __launch_bounds__(256, 2) void attn_mfma_kernel(
    const unsigned short* __restrict__ qhi,
    const unsigned short* __restrict__ Khi,
    const unsigned short* __restrict__ Vthi,
    unsigned short* __restrict__ AOhi) {
  __shared__ __align__(16) unsigned short sKh[64 * 64];
  __shared__ __align__(16) unsigned short sVh[64 * 64];
  __shared__ __align__(16) unsigned short sP[4][2][16][76];  // [wave][band][l-row][s-col]

  const int tid = threadIdx.x;
  const int wave = tid >> 6, lane = tid & 63;
  const int quad = lane >> 4, l16 = lane & 15;
  const int lB = blockIdx.x * 128;
  const int h = blockIdx.y, b = blockIdx.z;

  // Q fragments (A-layout); 0.125*log2e folded upstream
  short8 qh[2][2];
#pragma unroll
  for (int t = 0; t < 2; t++) {
    const size_t base =
        (size_t)(b * cL + lB + wave * 32 + t * 16 + l16) * cD + h * cHD + quad * 8;
    qh[t][0] = *(const short8*)(qhi + base);
    qh[t][1] = *(const short8*)(qhi + base + 32);
  }

  short8 ones;
#pragma unroll
  for (int i = 0; i < 8; i++) ones[i] = (short)0x3F80;  // bf16 1.0

  f32x4 O[2][4], dacc[2];
#pragma unroll
  for (int t = 0; t < 2; t++) {
#pragma unroll
    for (int i = 0; i < 4; i++) O[t][i] = (f32x4){0.f, 0.f, 0.f, 0.f};
    dacc[t] = (f32x4){0.f, 0.f, 0.f, 0.f};
  }

  const int srow8 = lane >> 3;        // row within 8-row staging slab
  const int sg = (lane & 7) ^ srow8;  // permuted global granule

  const int r0 = (wave * 2 + 0) * 8 + srow8;
  const int r1 = (wave * 2 + 1) * 8 + srow8;
  const size_t kb0 = (size_t)(b * cS + r0) * cD + h * cHD + sg * 8;  // + s*cD
  const size_t kb1 = (size_t)(b * cS + r1) * cD + h * cHD + sg * 8;
  const size_t vb0 = (size_t)(b * cD + h * cHD + r0) * cS + sg * 8;  // + s
  const size_t vb1 = (size_t)(b * cD + h * cHD + r1) * cS + sg * 8;

  // named prefetch registers (NO arrays -> stay in VGPRs; r4's array version spilled)
  uint4 k0h, v0h, k1h, v1h;
  k0h = *(const uint4*)(Khi + kb0);
  v0h = *(const uint4*)(Vthi + vb0);
  k1h = *(const uint4*)(Khi + kb1);
  v1h = *(const uint4*)(Vthi + vb1);

  const int j0 = wave * 2, j1 = wave * 2 + 1;

  for (int s0 = 0; s0 < cS; s0 += 64) {
    __syncthreads();  // all waves done reading LDS from prior chunk
    *(uint4*)&sKh[j0 * 512 + lane * 8] = k0h;
    *(uint4*)&sVh[j0 * 512 + lane * 8] = v0h;
    *(uint4*)&sKh[j1 * 512 + lane * 8] = k1h;
    *(uint4*)&sVh[j1 * 512 + lane * 8] = v1h;
    __syncthreads();

    // unconditional wrapped prefetch of next chunk
    {
      const int sn = (s0 + 64) & (cS - 1);
      const size_t kc = (size_t)sn * cD;
      k0h = *(const uint4*)(Khi + kb0 + kc);
      v0h = *(const uint4*)(Vthi + vb0 + sn);
      k1h = *(const uint4*)(Khi + kb1 + kc);
      v1h = *(const uint4*)(Vthi + vb1 + sn);
    }

    // QK^T single-bf16 (exp2 domain): each K-frag read feeds both l-bands
    f32x4 sc[2][4];
#pragma unroll
    for (int t = 0; t < 2; t++)
#pragma unroll
      for (int st = 0; st < 4; st++) sc[t][st] = (f32x4){0.f, 0.f, 0.f, 0.f};
#pragma unroll
    for (int st = 0; st < 4; st++) {
      const int srw = st * 16 + l16;
#pragma unroll
      for (int ks = 0; ks < 2; ks++) {
        const int slot = (ks * 4 + quad) ^ (srw & 7);
        const short8 kfh = *(const short8*)&sKh[srw * 64 + slot * 8];
        sc[0][st] = MFMA16(qh[0][ks], kfh, sc[0][st]);
        sc[1][st] = MFMA16(qh[1][ks], kfh, sc[1][st]);
      }
    }

    // P = exp2(sc) (static max: scores bounded ~3, no fp32 overflow over S), bf16 -> LDS
#pragma unroll
    for (int t = 0; t < 2; t++)
#pragma unroll
      for (int st = 0; st < 4; st++)
#pragma unroll
        for (int r = 0; r < 4; r++)
          sP[wave][t][quad * 4 + r][st * 16 + l16] =
              f2bf(__builtin_amdgcn_exp2f(sc[t][st][r]));

    // P fragments (A-layout), wave-local (compiler inserts lgkmcnt wait)
    short8 pfh[2][2];
#pragma unroll
    for (int t = 0; t < 2; t++) {
      pfh[t][0] = *(const short8*)&sP[wave][t][l16][quad * 8];
      pfh[t][1] = *(const short8*)&sP[wave][t][l16][32 + quad * 8];
    }

    // PV single-bf16: each V-frag read feeds both l-bands
#pragma unroll
    for (int dt = 0; dt < 4; dt++) {
      const int drw = dt * 16 + l16;
#pragma unroll
      for (int ss = 0; ss < 2; ss++) {
        const int slot = (ss * 4 + quad) ^ (drw & 7);
        const short8 vfh = *(const short8*)&sVh[drw * 64 + slot * 8];
        O[0][dt] = MFMA16(pfh[0][ss], vfh, O[0][dt]);
        O[1][dt] = MFMA16(pfh[1][ss], vfh, O[1][dt]);
      }
    }
    // denominators via ones-MFMA
#pragma unroll
    for (int t = 0; t < 2; t++) {
      dacc[t] = MFMA16(pfh[t][0], ones, dacc[t]);
      dacc[t] = MFMA16(pfh[t][1], ones, dacc[t]);
    }
  }

  // epilogue: row = quad*4+r, col = dt*16+l16; dacc col-replicated. AO hi-only.
#pragma unroll
  for (int t = 0; t < 2; t++) {
    float inv[4];
#pragma unroll
    for (int r = 0; r < 4; r++) inv[r] = 1.f / dacc[t][r];
#pragma unroll
    for (int dt = 0; dt < 4; dt++)
#pragma unroll
      for (int r = 0; r < 4; r++) {
        const size_t l = (size_t)(b * cL + lB + wave * 32 + t * 16 + quad * 4 + r);
        AOhi[l * cD + h * cHD + dt * 16 + l16] = f2bf(O[t][dt][r] * inv[r]);
      }
  }
}

}  // namespace

extern "C" void kernel_launch(void* const* d_in, const int* in_sizes, int n_in,
                              void* d_out, int out_size, void* d_ws, size_t ws_size,
                              hipStream_t stream) {
  (void)in_sizes; (void)n_in; (void)out_size; (void)ws_size;
  const float* x_q = (const float*)d_in[0];
  const int* x_idx = (const int*)d_in[1];
  const float* E_slots = (const float*)d_in[2];
  const float* rhos = (const float*)d_in[3];
  const float* C_seq = (const float*)d_in[4];
  const float* Wq = (const float*)d_in[5];
  const float* Wk = (const float*)d_in[6];
  const float* Wv = (const float*)d_in[7];
  const float* Wo = (const float*)d_in[8];
  const float* Wpe = (const float*)d_in[9];
  const float* ln_kv_g = (const float*)d_in[10];
  const float* ln_kv_b = (const float*)d_in[11];
  const float* ln_q_g = (const float*)d_in[12];
  const float* ln_q_b = (const float*)d_in[13];
  float* out = (float*)d_out;

  float* ws = (float*)d_ws;
  // float-unit offsets (ushort arrays occupy 2 entries per float slot)
  unsigned short* memhi = (unsigned short*)(ws + 0);         // 512K ushort
  unsigned short* Wkhi = (unsigned short*)(ws + 262144);     // 1M ushort each
  unsigned short* Wklo = (unsigned short*)(ws + 786432);
  unsigned short* Wvhi = (unsigned short*)(ws + 1310720);
  unsigned short* Wvlo = (unsigned short*)(ws + 1835008);
  float* gkv = ws + 2359296;                                 // 2M floats
  unsigned short* Wqhi = (unsigned short*)(ws + 4456448);
  unsigned short* Wqlo = (unsigned short*)(ws + 4980736);
  unsigned short* Wohi = (unsigned short*)(ws + 5505024);
  unsigned short* Wolo = (unsigned short*)(ws + 6029312);
  float* Ek = ws + 6553600;                                  // 512K floats
  float* Ev = ws + 7077888;
  unsigned short* Yhi = (unsigned short*)(ws + 7602176);     // 4M ushort (B*L*D)
  unsigned short* AOhi = (unsigned short*)(ws + 7602176);    // overlay Y (dead after Q GEMM)
  unsigned short* qhi = (unsigned short*)(ws + 9699328);     // 4M ushort
  unsigned short* Khi = (unsigned short*)(ws + 11796480);    // 4M ushort
  unsigned short* Vthi = (unsigned short*)(ws + 13893632);   // 4M ushort -> extent 64 MB

  constexpr float kQScale = 0.125f * 1.44269504088896340736f;  // 1/sqrt(HD) * log2(e)

  prep_all_kernel<<<8704, 256, 0, stream>>>(
      Wq, Wk, Wv, Wo, Wqhi, Wqlo, Wkhi, Wklo, Wvhi, Wvlo, Wohi, Wolo,
      E_slots, ln_kv_g, ln_kv_b, memhi, rhos, Wpe, gkv,
      x_q, C_seq, ln_q_g, ln_q_b, Yhi);
  gemm2_kernel<0><<<dim3(16, 4, 2), 256, 0, stream>>>(
      memhi, Wkhi, Wklo, Wvhi, Wvlo, Ek, Ev, nullptr, cNSLOT, cD, cD, 1.f);
  prep_kv_kernel<<<3072, 256, 0, stream>>>(Ek, Ev, gkv, x_idx, Khi, Vthi);
  gemm2_kernel<1><<<dim3(16, 32, 1), 256, 0, stream>>>(
      Yhi, Wqhi, Wqlo, Wqhi, Wqlo, nullptr, nullptr, qhi, cB * cL, cD, cD, kQScale);
  attn_mfma_kernel<<<dim3(cL / 128, cH, cB), 256, 0, stream>>>(qhi, Khi, Vthi, AOhi);
  gemm2_kernel<0><<<dim3(16, 32, 1), 256, 0, stream>>>(
      AOhi, Wohi, Wolo, Wohi, Wolo, out, out, nullptr, cB * cL, cD, cD, 1.f);
}

// Round 9
// 261.482 us; speedup vs baseline: 2.1598x; 1.0225x over previous
//
#include <hip/hip_runtime.h>
#include <cmath>
#include <cstddef>

namespace {

constexpr int cB = 2, cL = 2048, cS = 2048, cD = 1024, cH = 16, cNS = 8, cNSLOT = 512, cHD = 64;

typedef __attribute__((ext_vector_type(8))) short short8;
typedef __attribute__((ext_vector_type(4))) float f32x4;

#define MFMA16(a, b, c) __builtin_amdgcn_mfma_f32_16x16x32_bf16((a), (b), (c), 0, 0, 0)

__device__ __forceinline__ float sigmoidf_(float x) { return 1.f / (1.f + __expf(-x)); }

__device__ __forceinline__ unsigned short f2bf(float x) {
  union { float f; unsigned u; } c; c.f = x;
  unsigned r = c.u + 0x7FFFu + ((c.u >> 16) & 1u);
  return (unsigned short)(r >> 16);
}
__device__ __forceinline__ float bf2f(unsigned short h) {
  union { unsigned u; float f; } c; c.u = ((unsigned)h) << 16;
  return c.f;
}

// unpack 8 u32 (lo16|hi16 pairs) into two short8 fragments
__device__ __forceinline__ void unpack8(const uint4 a, const uint4 b, short8& p0, short8& p1) {
  const unsigned p[8] = {a.x, a.y, a.z, a.w, b.x, b.y, b.z, b.w};
  union { unsigned u[4]; short8 s; } H, L;
#pragma unroll
  for (int i = 0; i < 4; i++) {
    H.u[i] = __builtin_amdgcn_perm(p[2 * i + 1], p[2 * i], 0x05040100u);
    L.u[i] = __builtin_amdgcn_perm(p[2 * i + 1], p[2 * i], 0x07060302u);
  }
  p0 = H.s;
  p1 = L.s;
}

// async global->LDS 16B per lane. lds ptr must be wave-uniform base; HW writes base + lane*16.
__device__ __forceinline__ void async16(const void* g, void* l) {
  __builtin_amdgcn_global_load_lds((const __attribute__((address_space(1))) void*)g,
                                   (__attribute__((address_space(3))) void*)l, 16, 0, 0);
}

// ---------------- fused prep: wsplit | ln_slots | gatekv | qgate_ln ----------------
// grid 8704 x 256: [0,2048) weight split, [2048,2560) ln_slots, [2560,4608) gatekv,
// [4608,8704) qgate_ln.  Activations (mem, Y) emitted hi-only (2-term GEMMs downstream).
__global__ __launch_bounds__(256) void prep_all_kernel(
    const float* __restrict__ Wq, const float* __restrict__ Wk,
    const float* __restrict__ Wv, const float* __restrict__ Wo,
    unsigned short* __restrict__ Wqh, unsigned short* __restrict__ Wql,
    unsigned short* __restrict__ Wkh, unsigned short* __restrict__ Wkl,
    unsigned short* __restrict__ Wvh, unsigned short* __restrict__ Wvl,
    unsigned short* __restrict__ Woh, unsigned short* __restrict__ Wol,
    const float* __restrict__ E, const float* __restrict__ lnkv_g,
    const float* __restrict__ lnkv_b, unsigned short* __restrict__ mh,
    const float* __restrict__ rhos,
    const float* __restrict__ Wpe, float* __restrict__ gkv,
    const float* __restrict__ xq, const float* __restrict__ Cseq,
    const float* __restrict__ lnq_g, const float* __restrict__ lnq_b,
    unsigned short* __restrict__ Yh) {
  __shared__ float sC[cNS];
  __shared__ float rbuf[8];
  const int bid = blockIdx.x;
  const int tid = threadIdx.x;

  if (bid < 2048) {  // ---- weight split (weights keep hi+lo) ----
    const int wid = bid >> 9;
    const size_t off = ((size_t)(bid & 511) * 256 + tid) * 8;
    const float* src = wid == 0 ? Wq : wid == 1 ? Wk : wid == 2 ? Wv : Wo;
    unsigned short* dh = wid == 0 ? Wqh : wid == 1 ? Wkh : wid == 2 ? Wvh : Woh;
    unsigned short* dl = wid == 0 ? Wql : wid == 1 ? Wkl : wid == 2 ? Wvl : Wol;
    const float4 a = *(const float4*)(src + off);
    const float4 b = *(const float4*)(src + off + 4);
    float v[8] = {a.x, a.y, a.z, a.w, b.x, b.y, b.z, b.w};
    unsigned short h8[8], l8[8];
#pragma unroll
    for (int j = 0; j < 8; j++) {
      h8[j] = f2bf(v[j]);
      l8[j] = f2bf(v[j] - bf2f(h8[j]));
    }
    *(uint4*)(dh + off) = *(uint4*)h8;
    *(uint4*)(dl + off) = *(uint4*)l8;
  } else if (bid < 2560) {  // ---- ln_slots -> bf16 hi ----
    const int row = bid - 2048;
    const int d0 = tid * 4;
    const float4 x = *(const float4*)(E + (size_t)row * cD + d0);
    float s1 = x.x + x.y + x.z + x.w;
    float s2 = x.x * x.x + x.y * x.y + x.z * x.z + x.w * x.w;
#pragma unroll
    for (int o = 32; o > 0; o >>= 1) { s1 += __shfl_xor(s1, o, 64); s2 += __shfl_xor(s2, o, 64); }
    if ((tid & 63) == 0) { rbuf[tid >> 6] = s1; rbuf[4 + (tid >> 6)] = s2; }
    __syncthreads();
    s1 = rbuf[0] + rbuf[1] + rbuf[2] + rbuf[3];
    s2 = rbuf[4] + rbuf[5] + rbuf[6] + rbuf[7];
    const float mean = s1 * (1.f / cD);
    const float var = s2 * (1.f / cD) - mean * mean;
    const float inv = rsqrtf(var + 1e-5f);
    const float4 g = *(const float4*)(lnkv_g + d0);
    const float4 b = *(const float4*)(lnkv_b + d0);
    unsigned short h4[4];
    h4[0] = f2bf((x.x - mean) * inv * g.x + b.x);
    h4[1] = f2bf((x.y - mean) * inv * g.y + b.y);
    h4[2] = f2bf((x.z - mean) * inv * g.z + b.z);
    h4[3] = f2bf((x.w - mean) * inv * g.w + b.w);
    *(uint2*)(mh + (size_t)row * cD + d0) = *(uint2*)h4;
  } else if (bid < 4608) {  // ---- gatekv ----
    const int s = bid - 2560;
    if (tid < cNS) {
      const float age = (float)(cS - 1 - s);
      sC[tid] = __expf(age * __logf(rhos[tid]));
    }
    __syncthreads();
    const int d0 = tid * 4;
    float4 o4;
#pragma unroll
    for (int j = 0; j < 4; j++) {
      const float* wr = Wpe + (size_t)(d0 + j) * cNS;
      float gs = 0.f;
#pragma unroll
      for (int m = 0; m < cNS; m++) gs += sC[m] * wr[m];
      ((float*)&o4)[j] = gs * sigmoidf_(gs);
    }
    *(float4*)(gkv + (size_t)s * cD + d0) = o4;
  } else {  // ---- qgate_ln -> bf16 hi ----
    const int row = bid - 4608;
    if (tid < cNS) sC[tid] = Cseq[(size_t)row * cNS + tid];
    __syncthreads();
    const int d0 = tid * 4;
    const float4 x = *(const float4*)(xq + (size_t)row * cD + d0);
    float y[4];
    float s1 = 0.f, s2 = 0.f;
#pragma unroll
    for (int j = 0; j < 4; j++) {
      const float* wr = Wpe + (size_t)(d0 + j) * cNS;
      float gs = 0.f;
#pragma unroll
      for (int m = 0; m < cNS; m++) gs += sC[m] * wr[m];
      const float val = ((const float*)&x)[j] * gs * sigmoidf_(gs);
      y[j] = val;
      s1 += val;
      s2 += val * val;
    }
#pragma unroll
    for (int o = 32; o > 0; o >>= 1) { s1 += __shfl_xor(s1, o, 64); s2 += __shfl_xor(s2, o, 64); }
    if ((tid & 63) == 0) { rbuf[tid >> 6] = s1; rbuf[4 + (tid >> 6)] = s2; }
    __syncthreads();
    s1 = rbuf[0] + rbuf[1] + rbuf[2] + rbuf[3];
    s2 = rbuf[4] + rbuf[5] + rbuf[6] + rbuf[7];
    const float mean = s1 * (1.f / cD);
    const float var = s2 * (1.f / cD) - mean * mean;
    const float inv = rsqrtf(var + 1e-5f);
    const float4 g = *(const float4*)(lnq_g + d0);
    const float4 b = *(const float4*)(lnq_b + d0);
    unsigned short h4[4];
    h4[0] = f2bf((y[0] - mean) * inv * g.x + b.x);
    h4[1] = f2bf((y[1] - mean) * inv * g.y + b.y);
    h4[2] = f2bf((y[2] - mean) * inv * g.z + b.z);
    h4[3] = f2bf((y[3] - mean) * inv * g.w + b.w);
    *(uint2*)(Yh + (size_t)row * cD + d0) = *(uint2*)h4;
  }
}

// ---------------- shared 2-term GEMM body: C[128x64 tile] = A_hi @ (W_hi+W_lo)^T ----------------
// 256 thr (4 waves 2x2; wave = 64m x 32n), BK=32, double-buffered LDS, async staging.
template <int MODE>
__device__ __forceinline__ void gemm2_body(
    const unsigned short* __restrict__ Ahi,
    const unsigned short* __restrict__ Whi, const unsigned short* __restrict__ Wlo,
    float* __restrict__ Cf, unsigned short* __restrict__ Chi,
    int m0, int n0, int N, int K, float scale,
    unsigned short* sA, unsigned short* sBh, unsigned short* sBl) {
  const int tid = threadIdx.x;
  const int wave = tid >> 6, lane = tid & 63;
  const int quad = lane >> 4, l16 = lane & 15;
  const int wy = wave >> 1, wx = wave & 1;        // wave tile: 64(m) x 32(n)
  const int sg = (lane & 3) ^ ((lane >> 3) & 3);  // permuted global granule
  const int srow = lane >> 2;                     // row within a 16-row staging slab
  (void)srow;

  f32x4 acc[4][2];
#pragma unroll
  for (int i = 0; i < 4; i++)
#pragma unroll
    for (int j = 0; j < 2; j++) acc[i][j] = (f32x4){0.f, 0.f, 0.f, 0.f};

  auto stage = [&](int buf, int k0) {
#pragma unroll
    for (int c = 0; c < 2; c++) {
      const int row = c * 64 + wave * 16 + (lane >> 2);
      const size_t ga = (size_t)(m0 + row) * K + k0 + sg * 8;
      async16(Ahi + ga, sA + buf * 4096 + (c * 64 + wave * 16) * 32);
    }
    const int rowb = wave * 16 + (lane >> 2);
    const size_t gb = (size_t)(n0 + rowb) * K + k0 + sg * 8;
    async16(Whi + gb, sBh + buf * 2048 + wave * 16 * 32);
    async16(Wlo + gb, sBl + buf * 2048 + wave * 16 * 32);
  };

  stage(0, 0);
  __syncthreads();
  const int aswz = (l16 >> 1) & 3;
  int buf = 0;
  for (int k0 = 0; k0 < K; k0 += 32, buf ^= 1) {
    if (k0 + 32 < K) stage(buf ^ 1, k0 + 32);  // drains at iter-end barrier
    short8 bh[2], bl2[2];
#pragma unroll
    for (int tj = 0; tj < 2; tj++) {
      const int br = (wx * 32 + tj * 16 + l16) * 32 + ((quad ^ aswz) * 8);
      bh[tj] = *(const short8*)(sBh + buf * 2048 + br);
      bl2[tj] = *(const short8*)(sBl + buf * 2048 + br);
    }
#pragma unroll
    for (int ti = 0; ti < 4; ti++) {
      const int ar = (wy * 64 + ti * 16 + l16) * 32 + ((quad ^ aswz) * 8);
      const short8 ah = *(const short8*)(sA + buf * 4096 + ar);
#pragma unroll
      for (int tj = 0; tj < 2; tj++) {
        acc[ti][tj] = MFMA16(ah, bh[tj], acc[ti][tj]);
        acc[ti][tj] = MFMA16(ah, bl2[tj], acc[ti][tj]);
      }
    }
    __syncthreads();
  }

#pragma unroll
  for (int ti = 0; ti < 4; ti++)
#pragma unroll
    for (int tj = 0; tj < 2; tj++) {
      const int row = m0 + wy * 64 + ti * 16 + quad * 4;
      const int col = n0 + wx * 32 + tj * 16 + l16;
#pragma unroll
      for (int r = 0; r < 4; r++) {
        const size_t idx = (size_t)(row + r) * N + col;
        if constexpr (MODE == 0) {
          Cf[idx] = acc[ti][tj][r];
        } else {
          Chi[idx] = f2bf(acc[ti][tj][r] * scale);
        }
      }
    }
}

// ---------------- fused KV-proj + Q-proj GEMM dispatch ----------------
// 1D grid 640: [0,128) KV jobs (fp32 out, M=512), [128,640) Q job (bf16-hi out, scaled).
__global__ __launch_bounds__(256, 3) void gemm_qkv_kernel(
    const unsigned short* __restrict__ memhi,
    const unsigned short* __restrict__ Wkhi, const unsigned short* __restrict__ Wklo,
    const unsigned short* __restrict__ Wvhi, const unsigned short* __restrict__ Wvlo,
    float* __restrict__ Ek, float* __restrict__ Ev,
    const unsigned short* __restrict__ Yhi,
    const unsigned short* __restrict__ Wqhi, const unsigned short* __restrict__ Wqlo,
    unsigned short* __restrict__ qhi, float qscale) {
  __shared__ __align__(16) unsigned short sA[2 * 128 * 32];
  __shared__ __align__(16) unsigned short sBh[2 * 64 * 32];
  __shared__ __align__(16) unsigned short sBl[2 * 64 * 32];
  const int bid = blockIdx.x;
  if (bid < 128) {
    const int z = bid >> 6, rem = bid & 63;
    const int m0 = (rem >> 4) * 128, n0 = (rem & 15) * 64;
    gemm2_body<0>(memhi, z ? Wvhi : Wkhi, z ? Wvlo : Wklo, z ? Ev : Ek, nullptr,
                  m0, n0, cD, cD, 1.f, sA, sBh, sBl);
  } else {
    const int lid = bid - 128;
    const int m0 = (lid >> 4) * 128, n0 = (lid & 15) * 64;
    gemm2_body<1>(Yhi, Wqhi, Wqlo, nullptr, qhi, m0, n0, cD, cD, qscale, sA, sBh, sBl);
  }
}

// ---------------- O-projection GEMM ----------------
__global__ __launch_bounds__(256, 3) void gemm_o_kernel(
    const unsigned short* __restrict__ AOhi,
    const unsigned short* __restrict__ Wohi, const unsigned short* __restrict__ Wolo,
    float* __restrict__ out) {
  __shared__ __align__(16) unsigned short sA[2 * 128 * 32];
  __shared__ __align__(16) unsigned short sBh[2 * 64 * 32];
  __shared__ __align__(16) unsigned short sBl[2 * 64 * 32];
  gemm2_body<0>(AOhi, Wohi, Wolo, out, nullptr, blockIdx.y * 128, blockIdx.x * 64,
                cD, cD, 1.f, sA, sBh, sBl);
}

// ---------------- fused prep: K gather (row-major, hi) + Vt gather (transposed, hi) ----------------
// grid 3072 x 256: [0,2048) prep_k, [2048,3072) prep_vt.
__global__ __launch_bounds__(256) void prep_kv_kernel(
    const float* __restrict__ Ek, const float* __restrict__ Ev,
    const float* __restrict__ gkv, const int* __restrict__ xidx,
    unsigned short* __restrict__ Khi, unsigned short* __restrict__ Vthi) {
  __shared__ float tile[64][65];
  const int bid = blockIdx.x;
  const int tid = threadIdx.x;
  if (bid < 2048) {  // ---- prep_k ----
    const int t = bid * 256 + tid;
    const int d0 = (t & 127) * 8;
    const int s = (t >> 7) & (cS - 1);
    const int b = t >> 18;
    const int slot = xidx[b * cS + s];
    const float4 e0 = *(const float4*)(Ek + (size_t)slot * cD + d0);
    const float4 e1 = *(const float4*)(Ek + (size_t)slot * cD + d0 + 4);
    const float4 g0 = *(const float4*)(gkv + (size_t)s * cD + d0);
    const float4 g1 = *(const float4*)(gkv + (size_t)s * cD + d0 + 4);
    float v[8] = {e0.x * g0.x, e0.y * g0.y, e0.z * g0.z, e0.w * g0.w,
                  e1.x * g1.x, e1.y * g1.y, e1.z * g1.z, e1.w * g1.w};
    unsigned short h8[8];
#pragma unroll
    for (int j = 0; j < 8; j++) h8[j] = f2bf(v[j]);
    *(uint4*)(Khi + (size_t)(b * cS + s) * cD + d0) = *(uint4*)h8;
  } else {  // ---- prep_vt ----
    const int local = bid - 2048;
    const int s0 = (local & 31) * 64;
    const int d0 = ((local >> 5) & 15) * 64;
    const int b = local >> 9;
    const int sl = tid >> 4;
    const int dl = (tid & 15) * 4;
#pragma unroll
    for (int it = 0; it < 4; it++) {
      const int s = s0 + sl + it * 16;
      const int slot = xidx[b * cS + s];
      const float4 e = *(const float4*)(Ev + (size_t)slot * cD + d0 + dl);
      const float4 g = *(const float4*)(gkv + (size_t)s * cD + d0 + dl);
      tile[sl + it * 16][dl + 0] = e.x * g.x;
      tile[sl + it * 16][dl + 1] = e.y * g.y;
      tile[sl + it * 16][dl + 2] = e.z * g.z;
      tile[sl + it * 16][dl + 3] = e.w * g.w;
    }
    __syncthreads();
    const int dr = tid >> 3;
    const int sc = (tid & 7) * 8;
#pragma unroll
    for (int it = 0; it < 2; it++) {
      const int d = d0 + dr + it * 32;
      unsigned short h8[8];
#pragma unroll
      for (int j = 0; j < 8; j++) h8[j] = f2bf(tile[sc + j][dr + it * 32]);
      *(uint4*)(Vthi + (size_t)(b * cD + d) * cS + s0 + sc) = *(uint4*)h8;
    }
  }
}

// ---------------- MFMA flash attention v8: 2-wave blocks + band-packed P ----------------
// grid (L/64, H, B) = 1024 blocks, 128 thr = 2 waves, wave owns 32 l-rows (2 bands).
// s-chunk 64. LDS ~25KB -> 6 blocks/CU (12 waves) for bubble-filling.
// P band-pair packed into u32 (16 b32 writes vs 32 b16; reads carry both bands).
__global__ __launch_bounds__(128, 3) void attn_mfma_kernel(
    const unsigned short* __restrict__ qhi,
    const unsigned short* __restrict__ Khi,
    const unsigned short* __restrict__ Vthi,
    unsigned short* __restrict__ AOhi) {
  __shared__ __align__(16) unsigned short sKh[64 * 64];
  __shared__ __align__(16) unsigned short sVh[64 * 64];
  __shared__ __align__(16) unsigned int sP32[2][16][68];  // [wave][l-row][s-col] band0|band1

  const int tid = threadIdx.x;
  const int wave = tid >> 6, lane = tid & 63;
  const int quad = lane >> 4, l16 = lane & 15;
  const int lB = blockIdx.x * 64;
  const int h = blockIdx.y, b = blockIdx.z;

  // Q fragments (A-layout); 0.125*log2e folded upstream
  short8 qh[2][2];
#pragma unroll
  for (int t = 0; t < 2; t++) {
    const size_t base =
        (size_t)(b * cL + lB + wave * 32 + t * 16 + l16) * cD + h * cHD + quad * 8;
    qh[t][0] = *(const short8*)(qhi + base);
    qh[t][1] = *(const short8*)(qhi + base + 32);
  }

  short8 ones;
#pragma unroll
  for (int i = 0; i < 8; i++) ones[i] = (short)0x3F80;  // bf16 1.0

  f32x4 O[2][4], dacc[2];
#pragma unroll
  for (int t = 0; t < 2; t++) {
#pragma unroll
    for (int i = 0; i < 4; i++) O[t][i] = (f32x4){0.f, 0.f, 0.f, 0.f};
    dacc[t] = (f32x4){0.f, 0.f, 0.f, 0.f};
  }

  const int srow8 = lane >> 3;        // row within 8-row staging slab
  const int sg = (lane & 7) ^ srow8;  // permuted global granule

  // wave stages 4 K-slabs + 4 V-slabs (8 rows each)
  const int r0 = (wave * 4 + 0) * 8 + srow8;
  const int r1 = (wave * 4 + 1) * 8 + srow8;
  const int r2 = (wave * 4 + 2) * 8 + srow8;
  const int r3 = (wave * 4 + 3) * 8 + srow8;
  const size_t kb0 = (size_t)(b * cS + r0) * cD + h * cHD + sg * 8;
  const size_t kb1 = (size_t)(b * cS + r1) * cD + h * cHD + sg * 8;
  const size_t kb2 = (size_t)(b * cS + r2) * cD + h * cHD + sg * 8;
  const size_t kb3 = (size_t)(b * cS + r3) * cD + h * cHD + sg * 8;
  const size_t vb0 = (size_t)(b * cD + h * cHD + r0) * cS + sg * 8;
  const size_t vb1 = (size_t)(b * cD + h * cHD + r1) * cS + sg * 8;
  const size_t vb2 = (size_t)(b * cD + h * cHD + r2) * cS + sg * 8;
  const size_t vb3 = (size_t)(b * cD + h * cHD + r3) * cS + sg * 8;

  // named prefetch registers (NO arrays -> stay in VGPRs)
  uint4 k0, k1, k2, k3, v0, v1, v2, v3;
  k0 = *(const uint4*)(Khi + kb0);
  k1 = *(const uint4*)(Khi + kb1);
  k2 = *(const uint4*)(Khi + kb2);
  k3 = *(const uint4*)(Khi + kb3);
  v0 = *(const uint4*)(Vthi + vb0);
  v1 = *(const uint4*)(Vthi + vb1);
  v2 = *(const uint4*)(Vthi + vb2);
  v3 = *(const uint4*)(Vthi + vb3);

  const int j0 = wave * 4;

  for (int s0 = 0; s0 < cS; s0 += 64) {
    __syncthreads();  // all waves done reading LDS from prior chunk
    *(uint4*)&sKh[(j0 + 0) * 512 + lane * 8] = k0;
    *(uint4*)&sKh[(j0 + 1) * 512 + lane * 8] = k1;
    *(uint4*)&sKh[(j0 + 2) * 512 + lane * 8] = k2;
    *(uint4*)&sKh[(j0 + 3) * 512 + lane * 8] = k3;
    *(uint4*)&sVh[(j0 + 0) * 512 + lane * 8] = v0;
    *(uint4*)&sVh[(j0 + 1) * 512 + lane * 8] = v1;
    *(uint4*)&sVh[(j0 + 2) * 512 + lane * 8] = v2;
    *(uint4*)&sVh[(j0 + 3) * 512 + lane * 8] = v3;
    __syncthreads();

    // unconditional wrapped prefetch of next chunk
    {
      const int sn = (s0 + 64) & (cS - 1);
      const size_t kc = (size_t)sn * cD;
      k0 = *(const uint4*)(Khi + kb0 + kc);
      k1 = *(const uint4*)(Khi + kb1 + kc);
      k2 = *(const uint4*)(Khi + kb2 + kc);
      k3 = *(const uint4*)(Khi + kb3 + kc);
      v0 = *(const uint4*)(Vthi + vb0 + sn);
      v1 = *(const uint4*)(Vthi + vb1 + sn);
      v2 = *(const uint4*)(Vthi + vb2 + sn);
      v3 = *(const uint4*)(Vthi + vb3 + sn);
    }

    // QK^T single-bf16 (exp2 domain): each K-frag read feeds both l-bands
    f32x4 sc[2][4];
#pragma unroll
    for (int t = 0; t < 2; t++)
#pragma unroll
      for (int st = 0; st < 4; st++) sc[t][st] = (f32x4){0.f, 0.f, 0.f, 0.f};
#pragma unroll
    for (int st = 0; st < 4; st++) {
      const int srw = st * 16 + l16;
#pragma unroll
      for (int ks = 0; ks < 2; ks++) {
        const int slot = (ks * 4 + quad) ^ (srw & 7);
        const short8 kfh = *(const short8*)&sKh[srw * 64 + slot * 8];
        sc[0][st] = MFMA16(qh[0][ks], kfh, sc[0][st]);
        sc[1][st] = MFMA16(qh[1][ks], kfh, sc[1][st]);
      }
    }

    // P = exp2(sc) (static max: scores bounded ~3, no fp32 overflow over S),
    // band pair packed into u32 -> LDS
#pragma unroll
    for (int st = 0; st < 4; st++)
#pragma unroll
      for (int r = 0; r < 4; r++) {
        const unsigned u0 = f2bf(__builtin_amdgcn_exp2f(sc[0][st][r]));
        const unsigned u1 = f2bf(__builtin_amdgcn_exp2f(sc[1][st][r]));
        sP32[wave][quad * 4 + r][st * 16 + l16] = (u1 << 16) | u0;
      }

    // P fragments (A-layout), wave-local (compiler inserts lgkmcnt wait)
    short8 pf0[2], pf1[2];
#pragma unroll
    for (int ss = 0; ss < 2; ss++) {
      const uint4 pa = *(const uint4*)&sP32[wave][l16][ss * 32 + quad * 8];
      const uint4 pb = *(const uint4*)&sP32[wave][l16][ss * 32 + quad * 8 + 4];
      unpack8(pa, pb, pf0[ss], pf1[ss]);
    }

    // PV single-bf16: each V-frag read feeds both l-bands
#pragma unroll
    for (int dt = 0; dt < 4; dt++) {
      const int drw = dt * 16 + l16;
#pragma unroll
      for (int ss = 0; ss < 2; ss++) {
        const int slot = (ss * 4 + quad) ^ (drw & 7);
        const short8 vfh = *(const short8*)&sVh[drw * 64 + slot * 8];
        O[0][dt] = MFMA16(pf0[ss], vfh, O[0][dt]);
        O[1][dt] = MFMA16(pf1[ss], vfh, O[1][dt]);
      }
    }
    // denominators via ones-MFMA
    dacc[0] = MFMA16(pf0[0], ones, dacc[0]);
    dacc[0] = MFMA16(pf0[1], ones, dacc[0]);
    dacc[1] = MFMA16(pf1[0], ones, dacc[1]);
    dacc[1] = MFMA16(pf1[1], ones, dacc[1]);
  }

  // epilogue: row = quad*4+r, col = dt*16+l16; dacc col-replicated. AO hi-only.
#pragma unroll
  for (int t = 0; t < 2; t++) {
    float inv[4];
#pragma unroll
    for (int r = 0; r < 4; r++) inv[r] = 1.f / dacc[t][r];
#pragma unroll
    for (int dt = 0; dt < 4; dt++)
#pragma unroll
      for (int r = 0; r < 4; r++) {
        const size_t l = (size_t)(b * cL + lB + wave * 32 + t * 16 + quad * 4 + r);
        AOhi[l * cD + h * cHD + dt * 16 + l16] = f2bf(O[t][dt][r] * inv[r]);
      }
  }
}

}  // namespace

extern "C" void kernel_launch(void* const* d_in, const int* in_sizes, int n_in,
                              void* d_out, int out_size, void* d_ws, size_t ws_size,
                              hipStream_t stream) {
  (void)in_sizes; (void)n_in; (void)out_size; (void)ws_size;
  const float* x_q = (const float*)d_in[0];
  const int* x_idx = (const int*)d_in[1];
  const float* E_slots = (const float*)d_in[2];
  const float* rhos = (const float*)d_in[3];
  const float* C_seq = (const float*)d_in[4];
  const float* Wq = (const float*)d_in[5];
  const float* Wk = (const float*)d_in[6];
  const float* Wv = (const float*)d_in[7];
  const float* Wo = (const float*)d_in[8];
  const float* Wpe = (const float*)d_in[9];
  const float* ln_kv_g = (const float*)d_in[10];
  const float* ln_kv_b = (const float*)d_in[11];
  const float* ln_q_g = (const float*)d_in[12];
  const float* ln_q_b = (const float*)d_in[13];
  float* out = (float*)d_out;

  float* ws = (float*)d_ws;
  unsigned short* memhi = (unsigned short*)(ws + 0);         // 512K ushort
  unsigned short* Wkhi = (unsigned short*)(ws + 262144);     // 1M ushort each
  unsigned short* Wklo = (unsigned short*)(ws + 786432);
  unsigned short* Wvhi = (unsigned short*)(ws + 1310720);
  unsigned short* Wvlo = (unsigned short*)(ws + 1835008);
  float* gkv = ws + 2359296;                                 // 2M floats
  unsigned short* Wqhi = (unsigned short*)(ws + 4456448);
  unsigned short* Wqlo = (unsigned short*)(ws + 4980736);
  unsigned short* Wohi = (unsigned short*)(ws + 5505024);
  unsigned short* Wolo = (unsigned short*)(ws + 6029312);
  float* Ek = ws + 6553600;                                  // 512K floats
  float* Ev = ws + 7077888;
  unsigned short* Yhi = (unsigned short*)(ws + 7602176);     // 4M ushort (B*L*D)
  unsigned short* AOhi = (unsigned short*)(ws + 7602176);    // overlay Y (dead after Q GEMM)
  unsigned short* qhi = (unsigned short*)(ws + 9699328);     // 4M ushort
  unsigned short* Khi = (unsigned short*)(ws + 11796480);    // 4M ushort
  unsigned short* Vthi = (unsigned short*)(ws + 13893632);   // 4M ushort -> extent 64 MB

  constexpr float kQScale = 0.125f * 1.44269504088896340736f;  // 1/sqrt(HD) * log2(e)

  prep_all_kernel<<<8704, 256, 0, stream>>>(
      Wq, Wk, Wv, Wo, Wqhi, Wqlo, Wkhi, Wklo, Wvhi, Wvlo, Wohi, Wolo,
      E_slots, ln_kv_g, ln_kv_b, memhi, rhos, Wpe, gkv,
      x_q, C_seq, ln_q_g, ln_q_b, Yhi);
  gemm_qkv_kernel<<<640, 256, 0, stream>>>(
      memhi, Wkhi, Wklo, Wvhi, Wvlo, Ek, Ev, Yhi, Wqhi, Wqlo, qhi, kQScale);
  prep_kv_kernel<<<3072, 256, 0, stream>>>(Ek, Ev, gkv, x_idx, Khi, Vthi);
  attn_mfma_kernel<<<dim3(cL / 64, cH, cB), 128, 0, stream>>>(qhi, Khi, Vthi, AOhi);
  gemm_o_kernel<<<dim3(16, 32), 256, 0, stream>>>(AOhi, Wohi, Wolo, out);
}